// Round 1
// baseline (2745.405 us; speedup 1.0000x reference)
//
#include <hip/hip_runtime.h>
#include <math.h>

#define NB 4
#define SS 16
#define NN 1024        // H*W

__device__ __forceinline__ float sigm(float x) {
  return 1.0f / (1.0f + __expf(-x));
}
__device__ __forceinline__ float tanh_f(float x) {
  float e = __expf(2.0f * x);
  return 1.0f - 2.0f / (1.0f + e);
}

// ---------- prep: transposes + zero states ----------
__global__ void k0_prep(const float* __restrict__ conv_w, const float* __restrict__ z_w,
                        const float* __restrict__ m_w,
                        float* __restrict__ conv_wT, float* __restrict__ z_wT,
                        float* __restrict__ m_wT, float* __restrict__ h_A,
                        float* __restrict__ c_st) {
  int stride = gridDim.x * blockDim.x;
  int i0 = blockIdx.x * blockDim.x + threadIdx.x;
  for (int i = i0; i < 256*1152; i += stride) {
    int oc = i / 1152, k = i - oc*1152;
    conv_wT[k*256 + oc] = conv_w[i];
  }
  for (int i = i0; i < 128*128; i += stride) {
    int oc = i >> 7, k = i & 127;
    z_wT[k*128 + oc] = z_w[i];
  }
  for (int i = i0; i < 192*192; i += stride) {
    int oc = i / 192, k = i - oc*192;
    m_wT[k*192 + oc] = m_w[i];
  }
  for (int i = i0; i < NB*64*NN; i += stride) { h_A[i] = 0.0f; c_st[i] = 0.0f; }
}

// ---------- K1: conv + LSTM + projections ----------
__global__ __launch_bounds__(512) void k1_conv_lstm_proj(
    int t,
    const float* __restrict__ X, const float* __restrict__ conv_wT,
    const float* __restrict__ conv_b,
    const float* __restrict__ W_ci, const float* __restrict__ W_cf, const float* __restrict__ W_co,
    const float* __restrict__ qw, const float* __restrict__ qb,
    const float* __restrict__ kw, const float* __restrict__ kb,
    const float* __restrict__ k2w, const float* __restrict__ k2b,
    const float* __restrict__ vw, const float* __restrict__ vb,
    const float* __restrict__ v2w, const float* __restrict__ v2b,
    const float* __restrict__ h_cur, float* __restrict__ h_nxt,
    float* __restrict__ c_st,
    float* __restrict__ q_buf, float* __restrict__ kh_buf, float* __restrict__ km_buf,
    float* __restrict__ vhT, float* __restrict__ vmT)
{
  __shared__ float in_l[128*3*20];      // [ic][dy][20], cols 0..17 valid
  __shared__ float pw_l[176*68];        // packed proj weights, padded rows
  __shared__ float pb_l[176];
  __shared__ float gates_l[2*256*16];   // [icg][oc][x]
  __shared__ float h_l[16*68];          // [x][c]
  __shared__ float c_l[16*68];

  const int tid = threadIdx.x;
  const int bid = blockIdx.x;
  const int b  = bid >> 6;
  const int y  = (bid >> 1) & 31;
  const int xh = bid & 1;
  const int x0 = xh * 16;

  // stage input tile (128 ch x 3 rows x 18 cols, zero-padded)
  for (int idx = tid; idx < 128*3*18; idx += 512) {
    int col = idx % 18;
    int rest = idx / 18;
    int dy = rest % 3;
    int ic = rest / 3;
    int gy = y + dy - 1;
    int gx = x0 + col - 1;
    float v = 0.0f;
    if ((unsigned)gy < 32u && (unsigned)gx < 32u) {
      if (ic < 64) v = X[(((b*64 + ic)*SS + t)*NN) + gy*32 + gx];
      else         v = h_cur[((b*64 + (ic-64))*NN) + gy*32 + gx];
    }
    in_l[(ic*3 + dy)*20 + col] = v;
  }
  // stage packed projection weights: rows 0..15 q, 16..31 kh, 32..95 vh, 96..111 km, 112..175 vm
  for (int idx = tid; idx < 176*64; idx += 512) {
    int po = idx >> 6, c = idx & 63;
    float v;
    if (po < 16)       v = qw[po*64 + c];
    else if (po < 32)  v = kw[(po-16)*64 + c];
    else if (po < 96)  v = vw[(po-32)*64 + c];
    else if (po < 112) v = k2w[(po-96)*64 + c];
    else               v = v2w[(po-112)*64 + c];
    pw_l[po*68 + c] = v;
  }
  if (tid < 176) {
    int po = tid;
    float v;
    if (po < 16)       v = qb[po];
    else if (po < 32)  v = kb[po-16];
    else if (po < 96)  v = vb[po-32];
    else if (po < 112) v = k2b[po-96];
    else               v = v2b[po-112];
    pb_l[po] = v;
  }
  __syncthreads();

  // ---- phase A: conv (split K across icg halves) ----
  {
    const int oc  = tid & 255;
    const int icg = tid >> 8;      // 0: x-channels, 1: h-channels
    float acc[16];
    float bias = (icg == 0) ? conv_b[oc] : 0.0f;
    #pragma unroll
    for (int i = 0; i < 16; i++) acc[i] = bias;
    const float* wp = conv_wT + (icg*64*9)*256 + oc;
    const float* il = in_l + (icg*64*3)*20;
    for (int iy = 0; iy < 64*3; iy++) {
      const float* row = il + iy*20;
      float4 a0 = *(const float4*)(row);
      float4 a1 = *(const float4*)(row+4);
      float4 a2 = *(const float4*)(row+8);
      float4 a3 = *(const float4*)(row+12);
      float b16 = row[16], b17 = row[17];
      float in[18] = {a0.x,a0.y,a0.z,a0.w, a1.x,a1.y,a1.z,a1.w,
                      a2.x,a2.y,a2.z,a2.w, a3.x,a3.y,a3.z,a3.w, b16, b17};
      float w0 = wp[0], w1 = wp[256], w2 = wp[512];
      wp += 768;
      #pragma unroll
      for (int lx = 0; lx < 16; lx++)
        acc[lx] = fmaf(w0, in[lx], fmaf(w1, in[lx+1], fmaf(w2, in[lx+2], acc[lx])));
    }
    float* gl = &gates_l[(icg*256 + oc)*16];
    #pragma unroll
    for (int i = 0; i < 16; i += 4)
      *(float4*)(gl + i) = make_float4(acc[i], acc[i+1], acc[i+2], acc[i+3]);
  }
  __syncthreads();

  // ---- phase B: LSTM elementwise ----
  {
    const int c  = tid & 63;
    const int xq = tid >> 6;       // 0..7
    #pragma unroll
    for (int j = 0; j < 2; j++) {
      int x = xq*2 + j;
      int n = y*32 + x0 + x;
      float ig = gates_l[c*16 + x]          + gates_l[(256 + c)*16 + x];
      float fg = gates_l[(64 + c)*16 + x]   + gates_l[(256 + 64 + c)*16 + x];
      float gg = gates_l[(128 + c)*16 + x]  + gates_l[(256 + 128 + c)*16 + x];
      float og = gates_l[(192 + c)*16 + x]  + gates_l[(256 + 192 + c)*16 + x];
      float cp = c_st[(b*64 + c)*NN + n];
      float i_ = sigm(ig + W_ci[c*NN + n] * cp);
      float f_ = sigm(fg + W_cf[c*NN + n] * cp);
      float cn = f_*cp + i_*tanh_f(gg);
      float o_ = sigm(og + W_co[c*NN + n] * cn);
      float hn = o_*tanh_f(cn);
      h_nxt[(b*64 + c)*NN + n] = hn;
      c_st[(b*64 + c)*NN + n] = cn;
      h_l[x*68 + c] = hn;
      c_l[x*68 + c] = cn;
    }
  }
  __syncthreads();

  // ---- phase C: projections (q, kh, vh, km, vm) ----
  for (int r = 0; r < 6; r++) {
    int task = tid + r*512;
    if (task < 176*16) {
      int po = task >> 4, x = task & 15;
      const float* src = (po < 96) ? (h_l + x*68) : (c_l + x*68);
      const float* w = pw_l + po*68;
      float s = pb_l[po];
      #pragma unroll
      for (int k = 0; k < 64; k += 4) {
        float4 wv = *(const float4*)(w + k);
        float4 sv = *(const float4*)(src + k);
        s = fmaf(wv.x, sv.x, s); s = fmaf(wv.y, sv.y, s);
        s = fmaf(wv.z, sv.z, s); s = fmaf(wv.w, sv.w, s);
      }
      int n = y*32 + x0 + x;
      if (po < 16)        q_buf[(b*16 + po)*NN + n] = s;
      else if (po < 32)   kh_buf[(b*16 + po-16)*NN + n] = s;
      else if (po < 96)   vhT[(b*NN + n)*64 + (po-32)] = s;
      else if (po < 112)  km_buf[(b*16 + po-96)*NN + n] = s;
      else                vmT[(b*NN + n)*64 + (po-112)] = s;
    }
  }
}

// ---------- K2: dual attention + combine + gating ----------
__global__ __launch_bounds__(512) void k2_attn(
    int t,
    const float* __restrict__ q_buf, const float* __restrict__ kh_buf,
    const float* __restrict__ km_buf,
    const float* __restrict__ vhT, const float* __restrict__ vmT,
    float* __restrict__ h_nxt, float* __restrict__ c_st,
    const float* __restrict__ z_wT, const float* __restrict__ z_b,
    const float* __restrict__ m_wT, const float* __restrict__ m_b,
    float* __restrict__ out)
{
  __shared__ float q_l[16*16];        // [d][nl]
  __shared__ float s_l[16*1024];      // [nl][m]
  __shared__ float kv_l[128*64];      // union: kh chunk [d][128] / swizzled V chunk [mm][c]
  __shared__ float zhm_l[128*16];     // [zh;zm][nl]
  __shared__ float red_l[16*33];
  __shared__ float cb_in[192*16];     // [zz;hf][nl]
  __shared__ float cb_out[192*16];    // comb output [192][nl]

  const int tid = threadIdx.x;
  const int bid = blockIdx.x;
  // XCD-aware swizzle: blocks of the same batch land on the same pair of XCDs
  const int xcd = bid & 7;
  const int b = xcd >> 1;
  const int tile = ((bid >> 3) << 1) | (xcd & 1);   // 0..63
  const int n0 = tile * 16;

  if (tid < 256) {
    int d = tid >> 4, nl = tid & 15;
    q_l[d*16 + nl] = q_buf[(b*16 + d)*NN + n0 + nl];
  }
  __syncthreads();

  const int s_nl = tid >> 5;        // 0..15
  const int s_j  = tid & 31;        // 0..31
  const int p_cg = (tid >> 1) & 15;
  const int p_half = tid & 1;
  const int c0 = p_cg * 4;

  #pragma unroll 1
  for (int br = 0; br < 2; br++) {
    const float* kb_ = br ? km_buf : kh_buf;
    const float* vb_ = br ? vmT : vhT;
    // ---- scores ----
    float qreg[16];
    #pragma unroll
    for (int d = 0; d < 16; d++) qreg[d] = q_l[d*16 + s_nl];
    for (int mc = 0; mc < 8; mc++) {
      for (int idx = tid; idx < 2048; idx += 512) {
        int d = idx >> 7, mm = idx & 127;
        kv_l[d*128 + mm] = kb_[(b*16 + d)*NN + mc*128 + mm];
      }
      __syncthreads();
      #pragma unroll
      for (int r = 0; r < 4; r++) {
        int mm = s_j + 32*r;
        float s = 0.0f;
        #pragma unroll
        for (int d = 0; d < 16; d++) s = fmaf(qreg[d], kv_l[d*128 + mm], s);
        s_l[s_nl*1024 + mc*128 + mm] = s;
      }
      __syncthreads();
    }
    // ---- softmax (exact, two-pass) ----
    float mx = -3.0e38f;
    for (int k = s_j; k < 1024; k += 32) mx = fmaxf(mx, s_l[s_nl*1024 + k]);
    red_l[s_nl*33 + s_j] = mx;
    __syncthreads();
    float m16 = red_l[s_nl*33];
    #pragma unroll
    for (int k = 1; k < 32; k++) m16 = fmaxf(m16, red_l[s_nl*33 + k]);
    __syncthreads();
    float sum = 0.0f;
    for (int k = s_j; k < 1024; k += 32) {
      float e = __expf(s_l[s_nl*1024 + k] - m16);
      s_l[s_nl*1024 + k] = e;
      sum += e;
    }
    red_l[s_nl*33 + s_j] = sum;
    __syncthreads();
    float s16 = 0.0f;
    #pragma unroll
    for (int k = 0; k < 32; k++) s16 += red_l[s_nl*33 + k];
    float inv = 1.0f / s16;
    __syncthreads();
    // ---- PV ----
    float a0=0.f,a1=0.f,a2=0.f,a3=0.f;
    for (int mc = 0; mc < 8; mc++) {
      for (int idx = tid; idx < 2048; idx += 512) {
        int fi = idx*4;
        int mm = fi >> 6, cc = fi & 63;
        float4 v = *(const float4*)&vb_[(b*NN + mc*128 + mm)*64 + cc];
        int cs = cc ^ ((mm & 15) << 2);
        *(float4*)&kv_l[mm*64 + cs] = v;
      }
      __syncthreads();
      const int mmbase = p_half*64;
      #pragma unroll 4
      for (int mi = 0; mi < 64; mi += 4) {
        int mm = mmbase + mi;
        float4 p4 = *(const float4*)&s_l[s_nl*1024 + mc*128 + mm];
        #pragma unroll
        for (int jj = 0; jj < 4; jj++) {
          int m2 = mm + jj;
          const float4 v = *(const float4*)&kv_l[m2*64 + (c0 ^ ((m2 & 15) << 2))];
          float p = jj==0 ? p4.x : (jj==1 ? p4.y : (jj==2 ? p4.z : p4.w));
          a0 = fmaf(p, v.x, a0); a1 = fmaf(p, v.y, a1);
          a2 = fmaf(p, v.z, a2); a3 = fmaf(p, v.w, a3);
        }
      }
      __syncthreads();
    }
    if (p_half == 0) {
      zhm_l[(br*64 + c0 + 0)*16 + s_nl] = a0*inv;
      zhm_l[(br*64 + c0 + 1)*16 + s_nl] = a1*inv;
      zhm_l[(br*64 + c0 + 2)*16 + s_nl] = a2*inv;
      zhm_l[(br*64 + c0 + 3)*16 + s_nl] = a3*inv;
    }
    __syncthreads();
    if (p_half == 1) {
      zhm_l[(br*64 + c0 + 0)*16 + s_nl] += a0*inv;
      zhm_l[(br*64 + c0 + 1)*16 + s_nl] += a1*inv;
      zhm_l[(br*64 + c0 + 2)*16 + s_nl] += a2*inv;
      zhm_l[(br*64 + c0 + 3)*16 + s_nl] += a3*inv;
    }
    __syncthreads();
  }

  // ---- zz = z_w @ [zh; zm] + z_b ----
  {
    const int oc = tid & 127;
    const int h4 = tid >> 7;     // 0..3
    const int nl0 = h4 * 4;
    float z0 = z_b[oc], z1 = z0, z2 = z0, z3 = z0;
    for (int k = 0; k < 128; k++) {
      float w = z_wT[k*128 + oc];
      const float4 a = *(const float4*)&zhm_l[k*16 + nl0];
      z0 = fmaf(w, a.x, z0); z1 = fmaf(w, a.y, z1);
      z2 = fmaf(w, a.z, z2); z3 = fmaf(w, a.w, z3);
    }
    cb_in[oc*16 + nl0 + 0] = z0;
    cb_in[oc*16 + nl0 + 1] = z1;
    cb_in[oc*16 + nl0 + 2] = z2;
    cb_in[oc*16 + nl0 + 3] = z3;
  }
  for (int idx = tid; idx < 1024; idx += 512) {
    int c = idx >> 4, nl = idx & 15;
    cb_in[(128 + c)*16 + nl] = h_nxt[(b*64 + c)*NN + n0 + nl];
  }
  __syncthreads();
  // ---- comb = m_w @ [zz; hf] + m_b ----
  if (tid < 384) {
    const int oc = tid >> 1;      // 0..191
    const int half = tid & 1;
    const int nl0 = half * 8;
    float acc[8];
    float bb = m_b[oc];
    #pragma unroll
    for (int i = 0; i < 8; i++) acc[i] = bb;
    for (int k = 0; k < 192; k++) {
      float w = m_wT[k*192 + oc];
      const float4 v0 = *(const float4*)&cb_in[k*16 + nl0];
      const float4 v1 = *(const float4*)&cb_in[k*16 + nl0 + 4];
      acc[0] = fmaf(w, v0.x, acc[0]); acc[1] = fmaf(w, v0.y, acc[1]);
      acc[2] = fmaf(w, v0.z, acc[2]); acc[3] = fmaf(w, v0.w, acc[3]);
      acc[4] = fmaf(w, v1.x, acc[4]); acc[5] = fmaf(w, v1.y, acc[5]);
      acc[6] = fmaf(w, v1.z, acc[6]); acc[7] = fmaf(w, v1.w, acc[7]);
    }
    #pragma unroll
    for (int i = 0; i < 8; i++) cb_out[oc*16 + nl0 + i] = acc[i];
  }
  __syncthreads();
  // ---- gating: new_mf, new_hf, write state + output ----
  #pragma unroll
  for (int r = 0; r < 2; r++) {
    int task = tid + r*512;
    int c = task >> 4, nl = task & 15;
    int n = n0 + nl;
    float mo = cb_out[c*16 + nl];
    float mg = cb_out[(64 + c)*16 + nl];
    float mi = cb_out[(128 + c)*16 + nl];
    float mf = c_st[(b*64 + c)*NN + n];
    float mis = sigm(mi);
    float nmf = (1.0f - mis)*mf + mis*tanh_f(mg);
    float nhf = sigm(mo)*nmf;
    c_st[(b*64 + c)*NN + n] = nmf;
    h_nxt[(b*64 + c)*NN + n] = nhf;
    out[((b*64 + c)*SS + t)*NN + n] = nhf;
  }
}

extern "C" void kernel_launch(void* const* d_in, const int* in_sizes, int n_in,
                              void* d_out, int out_size, void* d_ws, size_t ws_size,
                              hipStream_t stream) {
  const float* X      = (const float*)d_in[0];
  const float* conv_w = (const float*)d_in[1];
  const float* conv_b = (const float*)d_in[2];
  const float* W_ci   = (const float*)d_in[3];
  const float* W_cf   = (const float*)d_in[4];
  const float* W_co   = (const float*)d_in[5];
  const float* qw  = (const float*)d_in[6];
  const float* qb  = (const float*)d_in[7];
  const float* kw  = (const float*)d_in[8];
  const float* kb  = (const float*)d_in[9];
  const float* k2w = (const float*)d_in[10];
  const float* k2b = (const float*)d_in[11];
  const float* vw  = (const float*)d_in[12];
  const float* vb  = (const float*)d_in[13];
  const float* v2w = (const float*)d_in[14];
  const float* v2b = (const float*)d_in[15];
  const float* z_w = (const float*)d_in[16];
  const float* z_b = (const float*)d_in[17];
  const float* m_w = (const float*)d_in[18];
  const float* m_b = (const float*)d_in[19];
  float* out = (float*)d_out;

  float* ws = (float*)d_ws;
  float* conv_wT = ws;            ws += 256*1152;
  float* z_wT    = ws;            ws += 128*128;
  float* m_wT    = ws;            ws += 192*192;
  float* h_A     = ws;            ws += NB*64*NN;
  float* h_B     = ws;            ws += NB*64*NN;
  float* c_st    = ws;            ws += NB*64*NN;
  float* q_buf   = ws;            ws += NB*16*NN;
  float* kh_buf  = ws;            ws += NB*16*NN;
  float* km_buf  = ws;            ws += NB*16*NN;
  float* vhT     = ws;            ws += NB*NN*64;
  float* vmT     = ws;            ws += NB*NN*64;

  hipLaunchKernelGGL(k0_prep, dim3(256), dim3(256), 0, stream,
                     conv_w, z_w, m_w, conv_wT, z_wT, m_wT, h_A, c_st);
  for (int t = 0; t < 16; t++) {
    const float* h_cur = (t & 1) ? h_B : h_A;
    float* h_nxt       = (t & 1) ? h_A : h_B;
    hipLaunchKernelGGL(k1_conv_lstm_proj, dim3(256), dim3(512), 0, stream,
        t, X, conv_wT, conv_b, W_ci, W_cf, W_co,
        qw, qb, kw, kb, k2w, k2b, vw, vb, v2w, v2b,
        h_cur, h_nxt, c_st, q_buf, kh_buf, km_buf, vhT, vmT);
    hipLaunchKernelGGL(k2_attn, dim3(256), dim3(512), 0, stream,
        t, q_buf, kh_buf, km_buf, vhT, vmT, h_nxt, c_st,
        z_wT, z_b, m_wT, m_b, out);
  }
}

// Round 2
// 1705.693 us; speedup vs baseline: 1.6096x; 1.6096x over previous
//
#include <hip/hip_runtime.h>
#include <math.h>

#define NB 4
#define SS 16
#define NN 1024        // H*W

__device__ __forceinline__ float sigm(float x) {
  return 1.0f / (1.0f + __expf(-x));
}
__device__ __forceinline__ float tanh_f(float x) {
  float e = __expf(2.0f * x);
  return 1.0f - 2.0f / (1.0f + e);
}

// ---------- prep: weight repacks + zero states ----------
__global__ void k0_prep(const float* __restrict__ conv_w, const float* __restrict__ z_w,
                        const float* __restrict__ m_w,
                        float* __restrict__ wT2, float* __restrict__ z_wT,
                        float* __restrict__ m_wT, float* __restrict__ h_A,
                        float* __restrict__ c_st) {
  int stride = gridDim.x * blockDim.x;
  int i0 = blockIdx.x * blockDim.x + threadIdx.x;
  // conv weights: [oc 256][k 1152] -> [k][ocq 64][4] with oc = ocq + 64*i
  for (int i = i0; i < 256*1152; i += stride) {
    int oc = i / 1152, k = i - oc*1152;
    wT2[(k*64 + (oc & 63))*4 + (oc >> 6)] = conv_w[i];
  }
  for (int i = i0; i < 128*128; i += stride) {
    int oc = i >> 7, k = i & 127;
    z_wT[k*128 + oc] = z_w[i];
  }
  for (int i = i0; i < 192*192; i += stride) {
    int oc = i / 192, k = i - oc*192;
    m_wT[k*192 + oc] = m_w[i];
  }
  for (int i = i0; i < NB*64*NN; i += stride) { h_A[i] = 0.0f; c_st[i] = 0.0f; }
}

// ---------- K1: conv + LSTM + projections (1024 threads) ----------
__global__ __launch_bounds__(1024, 4) void k1_conv_lstm_proj(
    int t,
    const float* __restrict__ X, const float* __restrict__ wT2,
    const float* __restrict__ conv_b,
    const float* __restrict__ W_ci, const float* __restrict__ W_cf, const float* __restrict__ W_co,
    const float* __restrict__ qw, const float* __restrict__ qb,
    const float* __restrict__ kw, const float* __restrict__ kb,
    const float* __restrict__ k2w, const float* __restrict__ k2b,
    const float* __restrict__ vw, const float* __restrict__ vb,
    const float* __restrict__ v2w, const float* __restrict__ v2b,
    const float* __restrict__ h_cur, float* __restrict__ h_nxt,
    float* __restrict__ c_st,
    float* __restrict__ q_buf, float* __restrict__ kh_buf, float* __restrict__ km_buf,
    float* __restrict__ vhT, float* __restrict__ vmT)
{
  __shared__ __align__(16) float in_l[384*20];       // [128ch*3dy][20], cols 0..17 valid
  __shared__ __align__(16) float gates2[2*256*16];   // [icg][oc][x]
  __shared__ __align__(16) float h_l[16*68];         // [x][c]
  __shared__ __align__(16) float c_l[16*68];

  const int tid = threadIdx.x;
  const int bid = blockIdx.x;
  const int b  = bid >> 6;
  const int y  = (bid >> 1) & 31;
  const int x0 = (bid & 1) * 16;

  // stage input tile (128 ch x 3 rows x 18 cols, zero-padded)
  for (int idx = tid; idx < 128*3*18; idx += 1024) {
    int col = idx % 18;
    int rest = idx / 18;
    int dy = rest % 3;
    int ic = rest / 3;
    int gy = y + dy - 1;
    int gx = x0 + col - 1;
    float v = 0.0f;
    if ((unsigned)gy < 32u && (unsigned)gx < 32u) {
      if (ic < 64) v = X[(((b*64 + ic)*SS + t)*NN) + gy*32 + gx];
      else         v = h_cur[((b*64 + (ic-64))*NN) + gy*32 + gx];
    }
    in_l[(ic*3 + dy)*20 + col] = v;
  }
  __syncthreads();

  // ---- conv: thread = ocq(64) x xq(4) x icg(2) x iyh(2); 4 oc x 4 x tile ----
  const int ocq = tid & 63;
  const int xq  = (tid >> 6) & 3;
  const int icg = (tid >> 8) & 1;
  const int iyh = tid >> 9;
  {
    float4 a0 = {0,0,0,0}, a1 = a0, a2 = a0, a3 = a0;
    const int row0 = icg*192 + iyh*96;
    for (int r = 0; r < 96; r++) {
      const int row = row0 + r;
      const float* rp = &in_l[row*20 + xq*4];
      float4 wa = *(const float4*)&rp[0];
      float2 wb = *(const float2*)&rp[4];
      const float w0v = wa.x, w1v = wa.y, w2v = wa.z, w3v = wa.w, w4v = wb.x, w5v = wb.y;
      const float* wp = &wT2[(row*3)*256 + ocq*4];
      float4 t0 = *(const float4*)&wp[0];
      float4 t1 = *(const float4*)&wp[256];
      float4 t2 = *(const float4*)&wp[512];
#define CSTEP(WT, I0, I1, I2, I3) \
      a0.x = fmaf(WT.x, I0, a0.x); a0.y = fmaf(WT.x, I1, a0.y); a0.z = fmaf(WT.x, I2, a0.z); a0.w = fmaf(WT.x, I3, a0.w); \
      a1.x = fmaf(WT.y, I0, a1.x); a1.y = fmaf(WT.y, I1, a1.y); a1.z = fmaf(WT.y, I2, a1.z); a1.w = fmaf(WT.y, I3, a1.w); \
      a2.x = fmaf(WT.z, I0, a2.x); a2.y = fmaf(WT.z, I1, a2.y); a2.z = fmaf(WT.z, I2, a2.z); a2.w = fmaf(WT.z, I3, a2.w); \
      a3.x = fmaf(WT.w, I0, a3.x); a3.y = fmaf(WT.w, I1, a3.y); a3.z = fmaf(WT.w, I2, a3.z); a3.w = fmaf(WT.w, I3, a3.w);
      CSTEP(t0, w0v, w1v, w2v, w3v)
      CSTEP(t1, w1v, w2v, w3v, w4v)
      CSTEP(t2, w2v, w3v, w4v, w5v)
#undef CSTEP
    }
    // accumulate partials: iyh0 writes, iyh1 adds
    if (iyh == 0) {
      *(float4*)&gates2[(icg*256 + ocq +   0)*16 + xq*4] = a0;
      *(float4*)&gates2[(icg*256 + ocq +  64)*16 + xq*4] = a1;
      *(float4*)&gates2[(icg*256 + ocq + 128)*16 + xq*4] = a2;
      *(float4*)&gates2[(icg*256 + ocq + 192)*16 + xq*4] = a3;
    }
    __syncthreads();
    if (iyh == 1) {
#define CADD(AV, OFF) { float4* g = (float4*)&gates2[(icg*256 + ocq + OFF)*16 + xq*4]; \
      float4 gv = *g; gv.x += AV.x; gv.y += AV.y; gv.z += AV.z; gv.w += AV.w; *g = gv; }
      CADD(a0, 0) CADD(a1, 64) CADD(a2, 128) CADD(a3, 192)
#undef CADD
    }
    __syncthreads();
  }

  // ---- LSTM elementwise: thread = (c 64) x (x 16) ----
  {
    const int x = tid & 15;
    const int c = tid >> 4;
    const int n = y*32 + x0 + x;
    const int gi = c*16 + x;
    float ig = gates2[gi]          + gates2[4096 + gi]          + conv_b[c];
    float fg = gates2[1024 + gi]   + gates2[4096 + 1024 + gi]   + conv_b[64 + c];
    float gg = gates2[2048 + gi]   + gates2[4096 + 2048 + gi]   + conv_b[128 + c];
    float og = gates2[3072 + gi]   + gates2[4096 + 3072 + gi]   + conv_b[192 + c];
    float cp = c_st[(b*64 + c)*NN + n];
    float i_ = sigm(ig + W_ci[c*NN + n] * cp);
    float f_ = sigm(fg + W_cf[c*NN + n] * cp);
    float cn = f_*cp + i_*tanh_f(gg);
    float o_ = sigm(og + W_co[c*NN + n] * cn);
    float hn = o_*tanh_f(cn);
    h_nxt[(b*64 + c)*NN + n] = hn;
    c_st[(b*64 + c)*NN + n] = cn;
    h_l[x*68 + c] = hn;
    c_l[x*68 + c] = cn;
  }
  __syncthreads();

  // ---- projections (q, kh, vh, km, vm); weights straight from L2 ----
  for (int r0 = 0; r0 < 3; r0++) {
    int task = tid + r0*1024;
    if (task < 176*16) {
      int po = task >> 4, x = task & 15;
      const float* src = (po < 96) ? &h_l[x*68] : &c_l[x*68];
      const float* w; float bias;
      if (po < 16)       { w = qw  + po*64;        bias = qb[po]; }
      else if (po < 32)  { w = kw  + (po-16)*64;   bias = kb[po-16]; }
      else if (po < 96)  { w = vw  + (po-32)*64;   bias = vb[po-32]; }
      else if (po < 112) { w = k2w + (po-96)*64;   bias = k2b[po-96]; }
      else               { w = v2w + (po-112)*64;  bias = v2b[po-112]; }
      float s = bias;
      #pragma unroll
      for (int k = 0; k < 64; k += 4) {
        float4 wv = *(const float4*)&w[k];
        float4 sv = *(const float4*)&src[k];
        s = fmaf(wv.x, sv.x, s); s = fmaf(wv.y, sv.y, s);
        s = fmaf(wv.z, sv.z, s); s = fmaf(wv.w, sv.w, s);
      }
      int n = y*32 + x0 + x;
      if (po < 16)        q_buf[(b*16 + po)*NN + n] = s;
      else if (po < 32)   kh_buf[(b*16 + po-16)*NN + n] = s;
      else if (po < 96)   vhT[(b*NN + n)*64 + (po-32)] = s;
      else if (po < 112)  km_buf[(b*16 + po-96)*NN + n] = s;
      else                vmT[(b*NN + n)*64 + (po-112)] = s;
    }
  }
}

// ---------- K2: dual attention (branch-parallel halves) + combine + gating ----------
__global__ __launch_bounds__(1024, 4) void k2_attn(
    int t,
    const float* __restrict__ q_buf, const float* __restrict__ kh_buf,
    const float* __restrict__ km_buf,
    const float* __restrict__ vhT, const float* __restrict__ vmT,
    float* __restrict__ h_nxt, float* __restrict__ c_st,
    const float* __restrict__ z_wT, const float* __restrict__ z_b,
    const float* __restrict__ m_wT, const float* __restrict__ m_b,
    float* __restrict__ out)
{
  __shared__ __align__(16) float q_l[256];        // [d][nl]
  __shared__ __align__(16) float kvR[2][8192];    // per branch: K chunk [16][128] / V chunk [128][64]
  __shared__ __align__(16) float p_c[2][2112];    // per branch: p chunk [16][132]
  __shared__ __align__(16) float zhm_l[2048];     // [128 rows zh;zm][16 nl]
  __shared__ __align__(16) float redcb[8192];     // red[2][4][16][64]  (later cb_in[3072]+cb_out[3072])
  __shared__ float invl[32];

  const int tid = threadIdx.x;
  const int bid = blockIdx.x;
  // XCD-aware swizzle: blocks of the same batch land on the same pair of XCDs
  const int xcd = bid & 7;
  const int b = xcd >> 1;
  const int tile = ((bid >> 3) << 1) | (xcd & 1);   // 0..63
  const int n0 = tile * 16;

  const int brh  = tid >> 9;      // which attention branch this half computes
  const int stid = tid & 511;

  if (tid < 256) q_l[tid] = q_buf[(b*16 + (tid >> 4))*NN + n0 + (tid & 15)];

  const float* kb_ = brh ? km_buf : kh_buf;
  const float* vb_ = brh ? vmT : vhT;
  float* Kc  = &kvR[brh][0];
  float* pC  = &p_c[brh][0];
  float* red = &redcb[brh*4096];

  const int nl = stid >> 5;       // 0..15
  const int j  = stid & 31;       // 0..31

  __syncthreads();                 // q_l ready

  float qreg[16];
  #pragma unroll
  for (int d = 0; d < 16; d++) qreg[d] = q_l[d*16 + nl];

  // ---- scores: 32 per thread, kept in registers ----
  float p[32];
  #pragma unroll
  for (int mc = 0; mc < 8; mc++) {
    #pragma unroll
    for (int it = 0; it < 4; it++) {
      int idx = stid + it*512;                 // 0..2047
      int d = idx >> 7, mm = idx & 127;
      Kc[d*128 + mm] = kb_[(b*16 + d)*NN + mc*128 + mm];
    }
    __syncthreads();
    #pragma unroll
    for (int r = 0; r < 4; r++) {
      float s = 0.0f;
      #pragma unroll
      for (int d = 0; d < 16; d++) s = fmaf(qreg[d], Kc[d*128 + j + 32*r], s);
      p[mc*4 + r] = s;
    }
    __syncthreads();
  }

  // ---- softmax in registers (width-32 shuffle reduce) ----
  float mx = p[0];
  #pragma unroll
  for (int i = 1; i < 32; i++) mx = fmaxf(mx, p[i]);
  mx = fmaxf(mx, __shfl_xor(mx, 16, 32));
  mx = fmaxf(mx, __shfl_xor(mx,  8, 32));
  mx = fmaxf(mx, __shfl_xor(mx,  4, 32));
  mx = fmaxf(mx, __shfl_xor(mx,  2, 32));
  mx = fmaxf(mx, __shfl_xor(mx,  1, 32));
  float sum = 0.0f;
  #pragma unroll
  for (int i = 0; i < 32; i++) { p[i] = __expf(p[i] - mx); sum += p[i]; }
  sum += __shfl_xor(sum, 16, 32);
  sum += __shfl_xor(sum,  8, 32);
  sum += __shfl_xor(sum,  4, 32);
  sum += __shfl_xor(sum,  2, 32);
  sum += __shfl_xor(sum,  1, 32);
  if (j == 0) invl[brh*16 + nl] = 1.0f / sum;

  // ---- PV: thread = mq(8) x nlg(4) x cg(16); 4 nl x 4 c register tile ----
  const int cg4 = (stid & 15) * 4;
  const int nlg = (stid >> 4) & 3;
  const int mq  = stid >> 6;
  float4 ac0 = {0,0,0,0}, ac1 = ac0, ac2 = ac0, ac3 = ac0;
  float* Vc = Kc;
  #pragma unroll
  for (int mc = 0; mc < 8; mc++) {
    __syncthreads();   // previous chunk's reads (or scores' Kc reads) done
    #pragma unroll
    for (int r = 0; r < 4; r++) pC[nl*132 + j + 32*r] = p[mc*4 + r];
    #pragma unroll
    for (int it = 0; it < 4; it++) {
      int idx = stid + it*512;                 // float4 slot 0..2047
      int mm = idx >> 4, c4 = (idx & 15)*4;
      *(float4*)&Vc[mm*64 + c4] = *(const float4*)&vb_[(b*NN + mc*128 + mm)*64 + c4];
    }
    __syncthreads();
    #pragma unroll
    for (int k0 = 0; k0 < 16; k0 += 4) {
      const int m0 = mq*16 + k0;
      float4 p0 = *(const float4*)&pC[(nlg*4 + 0)*132 + m0];
      float4 p1 = *(const float4*)&pC[(nlg*4 + 1)*132 + m0];
      float4 p2 = *(const float4*)&pC[(nlg*4 + 2)*132 + m0];
      float4 p3 = *(const float4*)&pC[(nlg*4 + 3)*132 + m0];
      #pragma unroll
      for (int d = 0; d < 4; d++) {
        float4 v = *(const float4*)&Vc[(m0 + d)*64 + cg4];
        float e0 = (d==0) ? p0.x : (d==1) ? p0.y : (d==2) ? p0.z : p0.w;
        float e1 = (d==0) ? p1.x : (d==1) ? p1.y : (d==2) ? p1.z : p1.w;
        float e2 = (d==0) ? p2.x : (d==1) ? p2.y : (d==2) ? p2.z : p2.w;
        float e3 = (d==0) ? p3.x : (d==1) ? p3.y : (d==2) ? p3.z : p3.w;
        ac0.x = fmaf(e0, v.x, ac0.x); ac0.y = fmaf(e0, v.y, ac0.y); ac0.z = fmaf(e0, v.z, ac0.z); ac0.w = fmaf(e0, v.w, ac0.w);
        ac1.x = fmaf(e1, v.x, ac1.x); ac1.y = fmaf(e1, v.y, ac1.y); ac1.z = fmaf(e1, v.z, ac1.z); ac1.w = fmaf(e1, v.w, ac1.w);
        ac2.x = fmaf(e2, v.x, ac2.x); ac2.y = fmaf(e2, v.y, ac2.y); ac2.z = fmaf(e2, v.z, ac2.z); ac2.w = fmaf(e2, v.w, ac2.w);
        ac3.x = fmaf(e3, v.x, ac3.x); ac3.y = fmaf(e3, v.y, ac3.y); ac3.z = fmaf(e3, v.z, ac3.z); ac3.w = fmaf(e3, v.w, ac3.w);
      }
    }
  }

  // ---- reduce 8 mq partials -> zhm ----
  if (mq < 4) {
    *(float4*)&red[(mq*16 + nlg*4 + 0)*64 + cg4] = ac0;
    *(float4*)&red[(mq*16 + nlg*4 + 1)*64 + cg4] = ac1;
    *(float4*)&red[(mq*16 + nlg*4 + 2)*64 + cg4] = ac2;
    *(float4*)&red[(mq*16 + nlg*4 + 3)*64 + cg4] = ac3;
  }
  __syncthreads();
  if (mq >= 4) {
#define RADD(AV, I) { float4* rr = (float4*)&red[((mq-4)*16 + nlg*4 + I)*64 + cg4]; \
    float4 rv = *rr; rv.x += AV.x; rv.y += AV.y; rv.z += AV.z; rv.w += AV.w; *rr = rv; }
    RADD(ac0, 0) RADD(ac1, 1) RADD(ac2, 2) RADD(ac3, 3)
#undef RADD
  }
  __syncthreads();
  #pragma unroll
  for (int r = 0; r < 2; r++) {
    int idx = stid*2 + r;
    int nlo = idx >> 6, co = idx & 63;
    float s = red[(nlo)*64 + co] + red[(16 + nlo)*64 + co]
            + red[(32 + nlo)*64 + co] + red[(48 + nlo)*64 + co];
    zhm_l[(brh*64 + co)*16 + nlo] = s * invl[brh*16 + nlo];
  }
  __syncthreads();

  // ---- zz = z_w @ [zh; zm] + z_b  (+ stage hf rows) ----
  {
    const int oc  = tid & 127;
    const int nl0 = (tid >> 7) * 2;
    float s0 = z_b[oc], s1 = s0;
    for (int k = 0; k < 128; k++) {
      float w = z_wT[k*128 + oc];
      float2 zz2 = *(const float2*)&zhm_l[k*16 + nl0];
      s0 = fmaf(w, zz2.x, s0); s1 = fmaf(w, zz2.y, s1);
    }
    redcb[oc*16 + nl0]     = s0;
    redcb[oc*16 + nl0 + 1] = s1;
    const int c = tid >> 4, nn = tid & 15;
    redcb[(128 + c)*16 + nn] = h_nxt[(b*64 + c)*NN + n0 + nn];
  }
  __syncthreads();

  // ---- comb = m_w @ [zz; hf] + m_b ----
  if (tid < 768) {
    const int oc = tid >> 2;
    const int nl0 = (tid & 3) * 4;
    float4 a; a.x = a.y = a.z = a.w = m_b[oc];
    for (int k = 0; k < 192; k++) {
      float w = m_wT[k*192 + oc];
      float4 v = *(const float4*)&redcb[k*16 + nl0];
      a.x = fmaf(w, v.x, a.x); a.y = fmaf(w, v.y, a.y);
      a.z = fmaf(w, v.z, a.z); a.w = fmaf(w, v.w, a.w);
    }
    *(float4*)&redcb[3072 + oc*16 + nl0] = a;
  }
  __syncthreads();

  // ---- gating ----
  {
    const int c = tid >> 4, nn = tid & 15;
    const int n = n0 + nn;
    float mo = redcb[3072 + c*16 + nn];
    float mg = redcb[3072 + (64 + c)*16 + nn];
    float mi = redcb[3072 + (128 + c)*16 + nn];
    float mf = c_st[(b*64 + c)*NN + n];
    float mis = sigm(mi);
    float nmf = (1.0f - mis)*mf + mis*tanh_f(mg);
    float nhf = sigm(mo)*nmf;
    c_st[(b*64 + c)*NN + n] = nmf;
    h_nxt[(b*64 + c)*NN + n] = nhf;
    out[((b*64 + c)*SS + t)*NN + n] = nhf;
  }
}

extern "C" void kernel_launch(void* const* d_in, const int* in_sizes, int n_in,
                              void* d_out, int out_size, void* d_ws, size_t ws_size,
                              hipStream_t stream) {
  const float* X      = (const float*)d_in[0];
  const float* conv_w = (const float*)d_in[1];
  const float* conv_b = (const float*)d_in[2];
  const float* W_ci   = (const float*)d_in[3];
  const float* W_cf   = (const float*)d_in[4];
  const float* W_co   = (const float*)d_in[5];
  const float* qw  = (const float*)d_in[6];
  const float* qb  = (const float*)d_in[7];
  const float* kw  = (const float*)d_in[8];
  const float* kb  = (const float*)d_in[9];
  const float* k2w = (const float*)d_in[10];
  const float* k2b = (const float*)d_in[11];
  const float* vw  = (const float*)d_in[12];
  const float* vb  = (const float*)d_in[13];
  const float* v2w = (const float*)d_in[14];
  const float* v2b = (const float*)d_in[15];
  const float* z_w = (const float*)d_in[16];
  const float* z_b = (const float*)d_in[17];
  const float* m_w = (const float*)d_in[18];
  const float* m_b = (const float*)d_in[19];
  float* out = (float*)d_out;

  float* ws = (float*)d_ws;
  float* wT2    = ws;             ws += 256*1152;
  float* z_wT   = ws;             ws += 128*128;
  float* m_wT   = ws;             ws += 192*192;
  float* h_A    = ws;             ws += NB*64*NN;
  float* h_B    = ws;             ws += NB*64*NN;
  float* c_st   = ws;             ws += NB*64*NN;
  float* q_buf  = ws;             ws += NB*16*NN;
  float* kh_buf = ws;             ws += NB*16*NN;
  float* km_buf = ws;             ws += NB*16*NN;
  float* vhT    = ws;             ws += NB*NN*64;
  float* vmT    = ws;             ws += NB*NN*64;

  hipLaunchKernelGGL(k0_prep, dim3(256), dim3(256), 0, stream,
                     conv_w, z_w, m_w, wT2, z_wT, m_wT, h_A, c_st);
  for (int t = 0; t < 16; t++) {
    const float* h_cur = (t & 1) ? h_B : h_A;
    float* h_nxt       = (t & 1) ? h_A : h_B;
    hipLaunchKernelGGL(k1_conv_lstm_proj, dim3(256), dim3(1024), 0, stream,
        t, X, wT2, conv_b, W_ci, W_cf, W_co,
        qw, qb, kw, kb, k2w, k2b, vw, vb, v2w, v2b,
        h_cur, h_nxt, c_st, q_buf, kh_buf, km_buf, vhT, vmT);
    hipLaunchKernelGGL(k2_attn, dim3(256), dim3(1024), 0, stream,
        t, q_buf, kh_buf, km_buf, vhT, vmT, h_nxt, c_st,
        z_wT, z_b, m_wT, m_b, out);
  }
}

// Round 3
// 1245.940 us; speedup vs baseline: 2.2035x; 1.3690x over previous
//
#include <hip/hip_runtime.h>
#include <math.h>

#define NB 4
#define SS 16
#define NN 1024        // H*W

typedef short s8v __attribute__((ext_vector_type(8)));    // 8 bf16 (4 VGPR)
typedef float f4v __attribute__((ext_vector_type(4)));    // MFMA accumulator

__device__ __forceinline__ float sigm(float x) {
  return 1.0f / (1.0f + __expf(-x));
}
__device__ __forceinline__ float tanh_f(float x) {
  float e = __expf(2.0f * x);
  return 1.0f - 2.0f / (1.0f + e);
}
__device__ __forceinline__ unsigned short bf16r(float x) {   // RNE float->bf16
  unsigned int u = __float_as_uint(x);
  u = (u + 0x7FFFu + ((u >> 16) & 1u)) >> 16;
  return (unsigned short)u;
}
__device__ __forceinline__ float bf16f(unsigned short h) {
  return __uint_as_float(((unsigned int)h) << 16);
}

// ---------- prep: weight split/pack + transposes + zero states ----------
// conv weights packed in MFMA A-frag order:
//   Whi/Wlo[((mt*36 + ks)*64 + lane)*8 + j] = bf16 of W[oc = mt*16 + (lane&15)]
//                                                      [k = ks*32 + (lane>>4)*8 + j]
__global__ void k0_prep(const float* __restrict__ conv_w, const float* __restrict__ z_w,
                        const float* __restrict__ m_w,
                        unsigned short* __restrict__ Whi, unsigned short* __restrict__ Wlo,
                        float* __restrict__ z_wT, float* __restrict__ m_wT,
                        float* __restrict__ h_A, float* __restrict__ c_st) {
  int stride = gridDim.x * blockDim.x;
  int i0 = blockIdx.x * blockDim.x + threadIdx.x;
  for (int i = i0; i < 256*1152; i += stride) {
    int oc = i / 1152, k = i - oc*1152;          // k = ic*9 + ky*3 + kx
    float v = conv_w[i];
    unsigned short hi = bf16r(v);
    unsigned short lo = bf16r(v - bf16f(hi));
    int mt = oc >> 4, i16 = oc & 15;
    int ks = k >> 5, kk = k & 31;
    int lane = i16 | ((kk >> 3) << 4);
    int pos = ((mt*36 + ks)*64 + lane)*8 + (kk & 7);
    Whi[pos] = hi;
    Wlo[pos] = lo;
  }
  for (int i = i0; i < 128*128; i += stride) {
    int oc = i >> 7, k = i & 127;
    z_wT[k*128 + oc] = z_w[i];
  }
  for (int i = i0; i < 192*192; i += stride) {
    int oc = i / 192, k = i - oc*192;
    m_wT[k*192 + oc] = m_w[i];
  }
  for (int i = i0; i < NB*64*NN; i += stride) { h_A[i] = 0.0f; c_st[i] = 0.0f; }
}

// ---------- K1: conv (MFMA split-bf16) + LSTM + projections (512 threads) ----------
__global__ __launch_bounds__(512) void k1_conv_lstm_proj(
    int t,
    const float* __restrict__ X,
    const unsigned short* __restrict__ Whi, const unsigned short* __restrict__ Wlo,
    const float* __restrict__ conv_b,
    const float* __restrict__ W_ci, const float* __restrict__ W_cf, const float* __restrict__ W_co,
    const float* __restrict__ qw, const float* __restrict__ qb,
    const float* __restrict__ kw, const float* __restrict__ kb,
    const float* __restrict__ k2w, const float* __restrict__ k2b,
    const float* __restrict__ vw, const float* __restrict__ vb,
    const float* __restrict__ v2w, const float* __restrict__ v2b,
    const float* __restrict__ h_cur, float* __restrict__ h_nxt,
    float* __restrict__ c_st,
    float* __restrict__ q_buf, float* __restrict__ kh_buf, float* __restrict__ km_buf,
    float* __restrict__ vhT, float* __restrict__ vmT)
{
  __shared__ __align__(16) float in_l[384*20];                 // [128ch*3dy][20], cols 0..17 valid
  __shared__ __align__(16) unsigned short Ihi_l[36*64*8];      // im2col in B-frag order
  __shared__ __align__(16) unsigned short Ilo_l[36*64*8];
  __shared__ __align__(16) float gates_l[256*17];              // [oc][x] (pad 17)
  __shared__ __align__(16) float h_l[16*68];                   // [x][c]
  __shared__ __align__(16) float c_l[16*68];

  const int tid = threadIdx.x;
  const int bid = blockIdx.x;
  const int b  = bid >> 6;
  const int y  = (bid >> 1) & 31;
  const int x0 = (bid & 1) * 16;

  // ---- phase 0: stage input strip (128 ch x 3 rows x 18 cols, zero-padded) ----
  for (int idx = tid; idx < 128*3*18; idx += 512) {
    int col = idx % 18;
    int rest = idx / 18;
    int dy = rest % 3;
    int ic = rest / 3;
    int gy = y + dy - 1;
    int gx = x0 + col - 1;
    float v = 0.0f;
    if ((unsigned)gy < 32u && (unsigned)gx < 32u) {
      if (ic < 64) v = X[(((b*64 + ic)*SS + t)*NN) + gy*32 + gx];
      else         v = h_cur[((b*64 + (ic-64))*NN) + gy*32 + gx];
    }
    in_l[(ic*3 + dy)*20 + col] = v;
  }
  __syncthreads();

  // ---- phase 1: build im2col fragments (hi/lo bf16) ----
  for (int idx = tid; idx < 128*3*18; idx += 512) {
    int c = idx % 18;
    int rest = idx / 18;
    int dy = rest % 3;
    int ic = rest / 3;
    float v = in_l[(ic*3 + dy)*20 + c];
    unsigned short hi = bf16r(v);
    unsigned short lo = bf16r(v - bf16f(hi));
    int kbase = ic*9 + dy*3;
    #pragma unroll
    for (int dx = 0; dx < 3; dx++) {
      int n = c - dx;
      if ((unsigned)n < 16u) {
        int k = kbase + dx;
        int ks = k >> 5, kk = k & 31;
        int pos = (ks*64 + (n | ((kk >> 3) << 4)))*8 + (kk & 7);
        Ihi_l[pos] = hi;
        Ilo_l[pos] = lo;
      }
    }
  }
  __syncthreads();

  // ---- phase 2: MFMA K-loop (8 waves x 2 m-tiles; 3-term split-bf16) ----
  {
    const int lane = tid & 63;
    const int wid  = tid >> 6;          // 0..7
    const int mt0 = wid*2, mt1 = mt0 + 1;
    f4v acc0 = {0.f, 0.f, 0.f, 0.f};
    f4v acc1 = {0.f, 0.f, 0.f, 0.f};
    const s8v* Ah0 = (const s8v*)Whi + (mt0*36)*64 + lane;
    const s8v* Al0 = (const s8v*)Wlo + (mt0*36)*64 + lane;
    const s8v* Ah1 = (const s8v*)Whi + (mt1*36)*64 + lane;
    const s8v* Al1 = (const s8v*)Wlo + (mt1*36)*64 + lane;
    const s8v* Bh  = (const s8v*)Ihi_l + lane;
    const s8v* Bl  = (const s8v*)Ilo_l + lane;
    #pragma unroll 2
    for (int ks = 0; ks < 36; ks++) {
      s8v a0h = Ah0[ks*64];
      s8v a0l = Al0[ks*64];
      s8v a1h = Ah1[ks*64];
      s8v a1l = Al1[ks*64];
      s8v bh  = Bh[ks*64];
      s8v bl  = Bl[ks*64];
      acc0 = __builtin_amdgcn_mfma_f32_16x16x32_bf16(a0h, bh, acc0, 0, 0, 0);
      acc1 = __builtin_amdgcn_mfma_f32_16x16x32_bf16(a1h, bh, acc1, 0, 0, 0);
      acc0 = __builtin_amdgcn_mfma_f32_16x16x32_bf16(a0l, bh, acc0, 0, 0, 0);
      acc1 = __builtin_amdgcn_mfma_f32_16x16x32_bf16(a1l, bh, acc1, 0, 0, 0);
      acc0 = __builtin_amdgcn_mfma_f32_16x16x32_bf16(a0h, bl, acc0, 0, 0, 0);
      acc1 = __builtin_amdgcn_mfma_f32_16x16x32_bf16(a1h, bl, acc1, 0, 0, 0);
    }
    // scatter accumulators to gates_l: C row = (lane>>4)*4 + reg, col = lane&15
    const int colx = lane & 15;
    const int rb   = (lane >> 4) * 4;
    #pragma unroll
    for (int r = 0; r < 4; r++) {
      gates_l[(mt0*16 + rb + r)*17 + colx] = acc0[r];
      gates_l[(mt1*16 + rb + r)*17 + colx] = acc1[r];
    }
  }
  __syncthreads();

  // ---- phase 3: LSTM elementwise (2 channels per thread) ----
  {
    const int x  = tid & 15;
    const int c2 = tid >> 4;      // 0..31
    const int n  = y*32 + x0 + x;
    #pragma unroll
    for (int j = 0; j < 2; j++) {
      int c = c2 + j*32;
      float ig = gates_l[(c      )*17 + x] + conv_b[c];
      float fg = gates_l[( 64 + c)*17 + x] + conv_b[ 64 + c];
      float gg = gates_l[(128 + c)*17 + x] + conv_b[128 + c];
      float og = gates_l[(192 + c)*17 + x] + conv_b[192 + c];
      float cp = c_st[(b*64 + c)*NN + n];
      float i_ = sigm(ig + W_ci[c*NN + n] * cp);
      float f_ = sigm(fg + W_cf[c*NN + n] * cp);
      float cn = f_*cp + i_*tanh_f(gg);
      float o_ = sigm(og + W_co[c*NN + n] * cn);
      float hn = o_*tanh_f(cn);
      h_nxt[(b*64 + c)*NN + n] = hn;
      c_st[(b*64 + c)*NN + n] = cn;
      h_l[x*68 + c] = hn;
      c_l[x*68 + c] = cn;
    }
  }
  __syncthreads();

  // ---- phase 4: projections (q, kh, vh, km, vm); weights straight from L2 ----
  for (int r0 = 0; r0 < 6; r0++) {
    int task = tid + r0*512;
    if (task < 176*16) {
      int po = task >> 4, x = task & 15;
      const float* src = (po < 96) ? &h_l[x*68] : &c_l[x*68];
      const float* w; float bias;
      if (po < 16)       { w = qw  + po*64;        bias = qb[po]; }
      else if (po < 32)  { w = kw  + (po-16)*64;   bias = kb[po-16]; }
      else if (po < 96)  { w = vw  + (po-32)*64;   bias = vb[po-32]; }
      else if (po < 112) { w = k2w + (po-96)*64;   bias = k2b[po-96]; }
      else               { w = v2w + (po-112)*64;  bias = v2b[po-112]; }
      float s = bias;
      #pragma unroll
      for (int k = 0; k < 64; k += 4) {
        float4 wv = *(const float4*)&w[k];
        float4 sv = *(const float4*)&src[k];
        s = fmaf(wv.x, sv.x, s); s = fmaf(wv.y, sv.y, s);
        s = fmaf(wv.z, sv.z, s); s = fmaf(wv.w, sv.w, s);
      }
      int n = y*32 + x0 + x;
      if (po < 16)        q_buf[(b*16 + po)*NN + n] = s;
      else if (po < 32)   kh_buf[(b*16 + po-16)*NN + n] = s;
      else if (po < 96)   vhT[(b*NN + n)*64 + (po-32)] = s;
      else if (po < 112)  km_buf[(b*16 + po-96)*NN + n] = s;
      else                vmT[(b*NN + n)*64 + (po-112)] = s;
    }
  }
}

// ---------- K2: dual attention (branch-parallel halves) + combine + gating ----------
__global__ __launch_bounds__(1024, 4) void k2_attn(
    int t,
    const float* __restrict__ q_buf, const float* __restrict__ kh_buf,
    const float* __restrict__ km_buf,
    const float* __restrict__ vhT, const float* __restrict__ vmT,
    float* __restrict__ h_nxt, float* __restrict__ c_st,
    const float* __restrict__ z_wT, const float* __restrict__ z_b,
    const float* __restrict__ m_wT, const float* __restrict__ m_b,
    float* __restrict__ out)
{
  __shared__ __align__(16) float q_l[256];        // [d][nl]
  __shared__ __align__(16) float kvR[2][8192];    // per branch: K chunk [16][128] / V chunk [128][64]
  __shared__ __align__(16) float p_c[2][2112];    // per branch: p chunk [16][132]
  __shared__ __align__(16) float zhm_l[2048];     // [128 rows zh;zm][16 nl]
  __shared__ __align__(16) float redcb[8192];     // red[2][4][16][64]  (later cb_in[3072]+cb_out[3072])
  __shared__ float invl[32];

  const int tid = threadIdx.x;
  const int bid = blockIdx.x;
  // XCD-aware swizzle: blocks of the same batch land on the same pair of XCDs
  const int xcd = bid & 7;
  const int b = xcd >> 1;
  const int tile = ((bid >> 3) << 1) | (xcd & 1);   // 0..63
  const int n0 = tile * 16;

  const int brh  = tid >> 9;      // which attention branch this half computes
  const int stid = tid & 511;

  if (tid < 256) q_l[tid] = q_buf[(b*16 + (tid >> 4))*NN + n0 + (tid & 15)];

  const float* kb_ = brh ? km_buf : kh_buf;
  const float* vb_ = brh ? vmT : vhT;
  float* Kc  = &kvR[brh][0];
  float* pC  = &p_c[brh][0];
  float* red = &redcb[brh*4096];

  const int nl = stid >> 5;       // 0..15
  const int j  = stid & 31;       // 0..31

  __syncthreads();                 // q_l ready

  float qreg[16];
  #pragma unroll
  for (int d = 0; d < 16; d++) qreg[d] = q_l[d*16 + nl];

  // ---- scores: 32 per thread, kept in registers ----
  float p[32];
  #pragma unroll
  for (int mc = 0; mc < 8; mc++) {
    #pragma unroll
    for (int it = 0; it < 4; it++) {
      int idx = stid + it*512;                 // 0..2047
      int d = idx >> 7, mm = idx & 127;
      Kc[d*128 + mm] = kb_[(b*16 + d)*NN + mc*128 + mm];
    }
    __syncthreads();
    #pragma unroll
    for (int r = 0; r < 4; r++) {
      float s = 0.0f;
      #pragma unroll
      for (int d = 0; d < 16; d++) s = fmaf(qreg[d], Kc[d*128 + j + 32*r], s);
      p[mc*4 + r] = s;
    }
    __syncthreads();
  }

  // ---- softmax in registers (width-32 shuffle reduce) ----
  float mx = p[0];
  #pragma unroll
  for (int i = 1; i < 32; i++) mx = fmaxf(mx, p[i]);
  mx = fmaxf(mx, __shfl_xor(mx, 16, 32));
  mx = fmaxf(mx, __shfl_xor(mx,  8, 32));
  mx = fmaxf(mx, __shfl_xor(mx,  4, 32));
  mx = fmaxf(mx, __shfl_xor(mx,  2, 32));
  mx = fmaxf(mx, __shfl_xor(mx,  1, 32));
  float sum = 0.0f;
  #pragma unroll
  for (int i = 0; i < 32; i++) { p[i] = __expf(p[i] - mx); sum += p[i]; }
  sum += __shfl_xor(sum, 16, 32);
  sum += __shfl_xor(sum,  8, 32);
  sum += __shfl_xor(sum,  4, 32);
  sum += __shfl_xor(sum,  2, 32);
  sum += __shfl_xor(sum,  1, 32);
  if (j == 0) invl[brh*16 + nl] = 1.0f / sum;

  // ---- PV: thread = mq(8) x nlg(4) x cg(16); 4 nl x 4 c register tile ----
  const int cg4 = (stid & 15) * 4;
  const int nlg = (stid >> 4) & 3;
  const int mq  = stid >> 6;
  float4 ac0 = {0,0,0,0}, ac1 = ac0, ac2 = ac0, ac3 = ac0;
  float* Vc = Kc;
  #pragma unroll
  for (int mc = 0; mc < 8; mc++) {
    __syncthreads();   // previous chunk's reads (or scores' Kc reads) done
    #pragma unroll
    for (int r = 0; r < 4; r++) pC[nl*132 + j + 32*r] = p[mc*4 + r];
    #pragma unroll
    for (int it = 0; it < 4; it++) {
      int idx = stid + it*512;                 // float4 slot 0..2047
      int mm = idx >> 4, c4 = (idx & 15)*4;
      *(float4*)&Vc[mm*64 + c4] = *(const float4*)&vb_[(b*NN + mc*128 + mm)*64 + c4];
    }
    __syncthreads();
    #pragma unroll
    for (int k0 = 0; k0 < 16; k0 += 4) {
      const int m0 = mq*16 + k0;
      float4 p0 = *(const float4*)&pC[(nlg*4 + 0)*132 + m0];
      float4 p1 = *(const float4*)&pC[(nlg*4 + 1)*132 + m0];
      float4 p2 = *(const float4*)&pC[(nlg*4 + 2)*132 + m0];
      float4 p3 = *(const float4*)&pC[(nlg*4 + 3)*132 + m0];
      #pragma unroll
      for (int d = 0; d < 4; d++) {
        float4 v = *(const float4*)&Vc[(m0 + d)*64 + cg4];
        float e0 = (d==0) ? p0.x : (d==1) ? p0.y : (d==2) ? p0.z : p0.w;
        float e1 = (d==0) ? p1.x : (d==1) ? p1.y : (d==2) ? p1.z : p1.w;
        float e2 = (d==0) ? p2.x : (d==1) ? p2.y : (d==2) ? p2.z : p2.w;
        float e3 = (d==0) ? p3.x : (d==1) ? p3.y : (d==2) ? p3.z : p3.w;
        ac0.x = fmaf(e0, v.x, ac0.x); ac0.y = fmaf(e0, v.y, ac0.y); ac0.z = fmaf(e0, v.z, ac0.z); ac0.w = fmaf(e0, v.w, ac0.w);
        ac1.x = fmaf(e1, v.x, ac1.x); ac1.y = fmaf(e1, v.y, ac1.y); ac1.z = fmaf(e1, v.z, ac1.z); ac1.w = fmaf(e1, v.w, ac1.w);
        ac2.x = fmaf(e2, v.x, ac2.x); ac2.y = fmaf(e2, v.y, ac2.y); ac2.z = fmaf(e2, v.z, ac2.z); ac2.w = fmaf(e2, v.w, ac2.w);
        ac3.x = fmaf(e3, v.x, ac3.x); ac3.y = fmaf(e3, v.y, ac3.y); ac3.z = fmaf(e3, v.z, ac3.z); ac3.w = fmaf(e3, v.w, ac3.w);
      }
    }
  }

  // ---- reduce 8 mq partials -> zhm ----
  if (mq < 4) {
    *(float4*)&red[(mq*16 + nlg*4 + 0)*64 + cg4] = ac0;
    *(float4*)&red[(mq*16 + nlg*4 + 1)*64 + cg4] = ac1;
    *(float4*)&red[(mq*16 + nlg*4 + 2)*64 + cg4] = ac2;
    *(float4*)&red[(mq*16 + nlg*4 + 3)*64 + cg4] = ac3;
  }
  __syncthreads();
  if (mq >= 4) {
#define RADD(AV, I) { float4* rr = (float4*)&red[((mq-4)*16 + nlg*4 + I)*64 + cg4]; \
    float4 rv = *rr; rv.x += AV.x; rv.y += AV.y; rv.z += AV.z; rv.w += AV.w; *rr = rv; }
    RADD(ac0, 0) RADD(ac1, 1) RADD(ac2, 2) RADD(ac3, 3)
#undef RADD
  }
  __syncthreads();
  #pragma unroll
  for (int r = 0; r < 2; r++) {
    int idx = stid*2 + r;
    int nlo = idx >> 6, co = idx & 63;
    float s = red[(nlo)*64 + co] + red[(16 + nlo)*64 + co]
            + red[(32 + nlo)*64 + co] + red[(48 + nlo)*64 + co];
    zhm_l[(brh*64 + co)*16 + nlo] = s * invl[brh*16 + nlo];
  }
  __syncthreads();

  // ---- zz = z_w @ [zh; zm] + z_b  (+ stage hf rows) ----
  {
    const int oc  = tid & 127;
    const int nl0 = (tid >> 7) * 2;
    float s0 = z_b[oc], s1 = s0;
    for (int k = 0; k < 128; k++) {
      float w = z_wT[k*128 + oc];
      float2 zz2 = *(const float2*)&zhm_l[k*16 + nl0];
      s0 = fmaf(w, zz2.x, s0); s1 = fmaf(w, zz2.y, s1);
    }
    redcb[oc*16 + nl0]     = s0;
    redcb[oc*16 + nl0 + 1] = s1;
    const int c = tid >> 4, nn = tid & 15;
    redcb[(128 + c)*16 + nn] = h_nxt[(b*64 + c)*NN + n0 + nn];
  }
  __syncthreads();

  // ---- comb = m_w @ [zz; hf] + m_b ----
  if (tid < 768) {
    const int oc = tid >> 2;
    const int nl0 = (tid & 3) * 4;
    float4 a; a.x = a.y = a.z = a.w = m_b[oc];
    for (int k = 0; k < 192; k++) {
      float w = m_wT[k*192 + oc];
      float4 v = *(const float4*)&redcb[k*16 + nl0];
      a.x = fmaf(w, v.x, a.x); a.y = fmaf(w, v.y, a.y);
      a.z = fmaf(w, v.z, a.z); a.w = fmaf(w, v.w, a.w);
    }
    *(float4*)&redcb[3072 + oc*16 + nl0] = a;
  }
  __syncthreads();

  // ---- gating ----
  {
    const int c = tid >> 4, nn = tid & 15;
    const int n = n0 + nn;
    float mo = redcb[3072 + c*16 + nn];
    float mg = redcb[3072 + (64 + c)*16 + nn];
    float mi = redcb[3072 + (128 + c)*16 + nn];
    float mf = c_st[(b*64 + c)*NN + n];
    float mis = sigm(mi);
    float nmf = (1.0f - mis)*mf + mis*tanh_f(mg);
    float nhf = sigm(mo)*nmf;
    c_st[(b*64 + c)*NN + n] = nmf;
    h_nxt[(b*64 + c)*NN + n] = nhf;
    out[((b*64 + c)*SS + t)*NN + n] = nhf;
  }
}

extern "C" void kernel_launch(void* const* d_in, const int* in_sizes, int n_in,
                              void* d_out, int out_size, void* d_ws, size_t ws_size,
                              hipStream_t stream) {
  const float* X      = (const float*)d_in[0];
  const float* conv_w = (const float*)d_in[1];
  const float* conv_b = (const float*)d_in[2];
  const float* W_ci   = (const float*)d_in[3];
  const float* W_cf   = (const float*)d_in[4];
  const float* W_co   = (const float*)d_in[5];
  const float* qw  = (const float*)d_in[6];
  const float* qb  = (const float*)d_in[7];
  const float* kw  = (const float*)d_in[8];
  const float* kb  = (const float*)d_in[9];
  const float* k2w = (const float*)d_in[10];
  const float* k2b = (const float*)d_in[11];
  const float* vw  = (const float*)d_in[12];
  const float* vb  = (const float*)d_in[13];
  const float* v2w = (const float*)d_in[14];
  const float* v2b = (const float*)d_in[15];
  const float* z_w = (const float*)d_in[16];
  const float* z_b = (const float*)d_in[17];
  const float* m_w = (const float*)d_in[18];
  const float* m_b = (const float*)d_in[19];
  float* out = (float*)d_out;

  float* ws = (float*)d_ws;
  unsigned short* Whi = (unsigned short*)ws;  ws += 147456;   // 294912 ushorts
  unsigned short* Wlo = (unsigned short*)ws;  ws += 147456;
  float* z_wT   = ws;             ws += 128*128;
  float* m_wT   = ws;             ws += 192*192;
  float* h_A    = ws;             ws += NB*64*NN;
  float* h_B    = ws;             ws += NB*64*NN;
  float* c_st   = ws;             ws += NB*64*NN;
  float* q_buf  = ws;             ws += NB*16*NN;
  float* kh_buf = ws;             ws += NB*16*NN;
  float* km_buf = ws;             ws += NB*16*NN;
  float* vhT    = ws;             ws += NB*NN*64;
  float* vmT    = ws;             ws += NB*NN*64;

  hipLaunchKernelGGL(k0_prep, dim3(256), dim3(256), 0, stream,
                     conv_w, z_w, m_w, Whi, Wlo, z_wT, m_wT, h_A, c_st);
  for (int t = 0; t < 16; t++) {
    const float* h_cur = (t & 1) ? h_B : h_A;
    float* h_nxt       = (t & 1) ? h_A : h_B;
    hipLaunchKernelGGL(k1_conv_lstm_proj, dim3(256), dim3(512), 0, stream,
        t, X, Whi, Wlo, conv_b, W_ci, W_cf, W_co,
        qw, qb, kw, kb, k2w, k2b, vw, vb, v2w, v2b,
        h_cur, h_nxt, c_st, q_buf, kh_buf, km_buf, vhT, vmT);
    hipLaunchKernelGGL(k2_attn, dim3(256), dim3(1024), 0, stream,
        t, q_buf, kh_buf, km_buf, vhT, vmT, h_nxt, c_st,
        z_wT, z_b, m_wT, m_b, out);
  }
}

// Round 4
// 902.461 us; speedup vs baseline: 3.0421x; 1.3806x over previous
//
#include <hip/hip_runtime.h>
#include <math.h>

#define NB 4
#define SS 16
#define NN 1024        // H*W

typedef short s8v __attribute__((ext_vector_type(8)));    // 8 bf16 (4 VGPR)
typedef float f4v __attribute__((ext_vector_type(4)));    // MFMA accumulator

__device__ __forceinline__ float sigm(float x) {
  return 1.0f / (1.0f + __expf(-x));
}
__device__ __forceinline__ float tanh_f(float x) {
  float e = __expf(2.0f * x);
  return 1.0f - 2.0f / (1.0f + e);
}
__device__ __forceinline__ unsigned short bf16r(float x) {   // RNE float->bf16
  unsigned int u = __float_as_uint(x);
  u = (u + 0x7FFFu + ((u >> 16) & 1u)) >> 16;
  return (unsigned short)u;
}
__device__ __forceinline__ float bf16f(unsigned short h) {
  return __uint_as_float(((unsigned int)h) << 16);
}

// ---------- prep: conv-weight split/pack + transposes + zero states ----------
__global__ void k0_prep(const float* __restrict__ conv_w, const float* __restrict__ z_w,
                        const float* __restrict__ m_w,
                        unsigned short* __restrict__ Whi, unsigned short* __restrict__ Wlo,
                        float* __restrict__ z_wT, float* __restrict__ m_wT,
                        float* __restrict__ h_A, float* __restrict__ c_st) {
  int stride = gridDim.x * blockDim.x;
  int i0 = blockIdx.x * blockDim.x + threadIdx.x;
  for (int i = i0; i < 256*1152; i += stride) {
    int oc = i / 1152, k = i - oc*1152;          // k = ic*9 + ky*3 + kx
    float v = conv_w[i];
    unsigned short hi = bf16r(v);
    unsigned short lo = bf16r(v - bf16f(hi));
    int mt = oc >> 4, i16 = oc & 15;
    int ks = k >> 5, kk = k & 31;
    int lane = i16 | ((kk >> 3) << 4);
    int pos = ((mt*36 + ks)*64 + lane)*8 + (kk & 7);
    Whi[pos] = hi;
    Wlo[pos] = lo;
  }
  for (int i = i0; i < 128*128; i += stride) {
    int oc = i >> 7, k = i & 127;
    z_wT[k*128 + oc] = z_w[i];
  }
  for (int i = i0; i < 192*192; i += stride) {
    int oc = i / 192, k = i - oc*192;
    m_wT[k*192 + oc] = m_w[i];
  }
  for (int i = i0; i < NB*64*NN; i += stride) { h_A[i] = 0.0f; c_st[i] = 0.0f; }
}

// ---------- K1: conv (MFMA split-bf16) + LSTM + projections (512 threads) ----------
__global__ __launch_bounds__(512) void k1_conv_lstm_proj(
    int t,
    const float* __restrict__ X,
    const unsigned short* __restrict__ Whi, const unsigned short* __restrict__ Wlo,
    const float* __restrict__ conv_b,
    const float* __restrict__ W_ci, const float* __restrict__ W_cf, const float* __restrict__ W_co,
    const float* __restrict__ qw, const float* __restrict__ qb,
    const float* __restrict__ kw, const float* __restrict__ kb,
    const float* __restrict__ k2w, const float* __restrict__ k2b,
    const float* __restrict__ vw, const float* __restrict__ vb,
    const float* __restrict__ v2w, const float* __restrict__ v2b,
    const float* __restrict__ h_cur, float* __restrict__ h_nxt,
    float* __restrict__ c_st,
    float* __restrict__ q_buf,
    unsigned short* __restrict__ kF,
    unsigned short* __restrict__ vFh, unsigned short* __restrict__ vFl)
{
  __shared__ __align__(16) float in_l[384*20];                 // [128ch*3dy][20], cols 0..17 valid
  __shared__ __align__(16) unsigned short Ihi_l[36*64*8];      // im2col in B-frag order
  __shared__ __align__(16) unsigned short Ilo_l[36*64*8];
  __shared__ __align__(16) float gates_l[256*17];              // [oc][x] (pad 17)
  __shared__ __align__(16) float h_l[16*68];                   // [x][c]
  __shared__ __align__(16) float c_l[16*68];

  const int tid = threadIdx.x;
  const int bid = blockIdx.x;
  const int b  = bid >> 6;
  const int y  = (bid >> 1) & 31;
  const int x0 = (bid & 1) * 16;

  // ---- phase 0: stage input strip (128 ch x 3 rows x 18 cols, zero-padded) ----
  for (int idx = tid; idx < 128*3*18; idx += 512) {
    int col = idx % 18;
    int rest = idx / 18;
    int dy = rest % 3;
    int ic = rest / 3;
    int gy = y + dy - 1;
    int gx = x0 + col - 1;
    float v = 0.0f;
    if ((unsigned)gy < 32u && (unsigned)gx < 32u) {
      if (ic < 64) v = X[(((b*64 + ic)*SS + t)*NN) + gy*32 + gx];
      else         v = h_cur[((b*64 + (ic-64))*NN) + gy*32 + gx];
    }
    in_l[(ic*3 + dy)*20 + col] = v;
  }
  __syncthreads();

  // ---- phase 1: build im2col fragments (hi/lo bf16) ----
  for (int idx = tid; idx < 128*3*18; idx += 512) {
    int c = idx % 18;
    int rest = idx / 18;
    int dy = rest % 3;
    int ic = rest / 3;
    float v = in_l[(ic*3 + dy)*20 + c];
    unsigned short hi = bf16r(v);
    unsigned short lo = bf16r(v - bf16f(hi));
    int kbase = ic*9 + dy*3;
    #pragma unroll
    for (int dx = 0; dx < 3; dx++) {
      int n = c - dx;
      if ((unsigned)n < 16u) {
        int k = kbase + dx;
        int ks = k >> 5, kk = k & 31;
        int pos = (ks*64 + (n | ((kk >> 3) << 4)))*8 + (kk & 7);
        Ihi_l[pos] = hi;
        Ilo_l[pos] = lo;
      }
    }
  }
  __syncthreads();

  // ---- phase 2: MFMA K-loop (8 waves x 2 m-tiles; 3-term split-bf16) ----
  {
    const int lane = tid & 63;
    const int wid  = tid >> 6;          // 0..7
    const int mt0 = wid*2, mt1 = mt0 + 1;
    f4v acc0 = {0.f, 0.f, 0.f, 0.f};
    f4v acc1 = {0.f, 0.f, 0.f, 0.f};
    const s8v* Ah0 = (const s8v*)Whi + (mt0*36)*64 + lane;
    const s8v* Al0 = (const s8v*)Wlo + (mt0*36)*64 + lane;
    const s8v* Ah1 = (const s8v*)Whi + (mt1*36)*64 + lane;
    const s8v* Al1 = (const s8v*)Wlo + (mt1*36)*64 + lane;
    const s8v* Bh  = (const s8v*)Ihi_l + lane;
    const s8v* Bl  = (const s8v*)Ilo_l + lane;
    #pragma unroll 2
    for (int ks = 0; ks < 36; ks++) {
      s8v a0h = Ah0[ks*64];
      s8v a0l = Al0[ks*64];
      s8v a1h = Ah1[ks*64];
      s8v a1l = Al1[ks*64];
      s8v bh  = Bh[ks*64];
      s8v bl  = Bl[ks*64];
      acc0 = __builtin_amdgcn_mfma_f32_16x16x32_bf16(a0h, bh, acc0, 0, 0, 0);
      acc1 = __builtin_amdgcn_mfma_f32_16x16x32_bf16(a1h, bh, acc1, 0, 0, 0);
      acc0 = __builtin_amdgcn_mfma_f32_16x16x32_bf16(a0l, bh, acc0, 0, 0, 0);
      acc1 = __builtin_amdgcn_mfma_f32_16x16x32_bf16(a1l, bh, acc1, 0, 0, 0);
      acc0 = __builtin_amdgcn_mfma_f32_16x16x32_bf16(a0h, bl, acc0, 0, 0, 0);
      acc1 = __builtin_amdgcn_mfma_f32_16x16x32_bf16(a1h, bl, acc1, 0, 0, 0);
    }
    const int colx = lane & 15;
    const int rb   = (lane >> 4) * 4;
    #pragma unroll
    for (int r = 0; r < 4; r++) {
      gates_l[(mt0*16 + rb + r)*17 + colx] = acc0[r];
      gates_l[(mt1*16 + rb + r)*17 + colx] = acc1[r];
    }
  }
  __syncthreads();

  // ---- phase 3: LSTM elementwise (2 channels per thread) ----
  {
    const int x  = tid & 15;
    const int c2 = tid >> 4;      // 0..31
    const int n  = y*32 + x0 + x;
    #pragma unroll
    for (int j = 0; j < 2; j++) {
      int c = c2 + j*32;
      float ig = gates_l[(c      )*17 + x] + conv_b[c];
      float fg = gates_l[( 64 + c)*17 + x] + conv_b[ 64 + c];
      float gg = gates_l[(128 + c)*17 + x] + conv_b[128 + c];
      float og = gates_l[(192 + c)*17 + x] + conv_b[192 + c];
      float cp = c_st[(b*64 + c)*NN + n];
      float i_ = sigm(ig + W_ci[c*NN + n] * cp);
      float f_ = sigm(fg + W_cf[c*NN + n] * cp);
      float cn = f_*cp + i_*tanh_f(gg);
      float o_ = sigm(og + W_co[c*NN + n] * cn);
      float hn = o_*tanh_f(cn);
      h_nxt[(b*64 + c)*NN + n] = hn;
      c_st[(b*64 + c)*NN + n] = cn;
      h_l[x*68 + c] = hn;
      c_l[x*68 + c] = cn;
    }
  }
  __syncthreads();

  // ---- phase 4: projections; K/V written in MFMA B-frag bf16 hi/lo order ----
  for (int r0 = 0; r0 < 6; r0++) {
    int task = tid + r0*512;
    if (task < 176*16) {
      int po = task >> 4, x = task & 15;
      const float* src = (po < 96) ? &h_l[x*68] : &c_l[x*68];
      const float* w; float bias;
      if (po < 16)       { w = qw  + po*64;        bias = qb[po]; }
      else if (po < 32)  { w = kw  + (po-16)*64;   bias = kb[po-16]; }
      else if (po < 96)  { w = vw  + (po-32)*64;   bias = vb[po-32]; }
      else if (po < 112) { w = k2w + (po-96)*64;   bias = k2b[po-96]; }
      else               { w = v2w + (po-112)*64;  bias = v2b[po-112]; }
      float s = bias;
      #pragma unroll
      for (int k = 0; k < 64; k += 4) {
        float4 wv = *(const float4*)&w[k];
        float4 sv = *(const float4*)&src[k];
        s = fmaf(wv.x, sv.x, s); s = fmaf(wv.y, sv.y, s);
        s = fmaf(wv.z, sv.z, s); s = fmaf(wv.w, sv.w, s);
      }
      int n = y*32 + x0 + x;
      if (po < 16) {
        q_buf[(b*16 + po)*NN + n] = s;
      } else {
        unsigned short hi = bf16r(s);
        unsigned short lo = bf16r(s - bf16f(hi));
        if (po < 32) {            // kh -> branch 0: B = [Kh | Kl] over k=0..31
          int d = po - 16;
          int mt = n >> 4;
          int base = ((b*2 + 0)*64 + mt)*64*8;
          int lh = (n & 15) | ((d >> 3) << 4);
          kF[base + lh*8 + (d & 7)] = hi;
          kF[base + (lh + 32)*8 + (d & 7)] = lo;
        } else if (po < 96) {     // vh -> branch 0 V-frags
          int c = po - 32;
          int ks = n >> 5, g = (n >> 3) & 3, j = n & 7, nt = c >> 4;
          int idx = ((((b*2 + 0)*32 + ks)*4 + nt)*64 + ((c & 15) | (g << 4)))*8 + j;
          vFh[idx] = hi; vFl[idx] = lo;
        } else if (po < 112) {    // km -> branch 1
          int d = po - 96;
          int mt = n >> 4;
          int base = ((b*2 + 1)*64 + mt)*64*8;
          int lh = (n & 15) | ((d >> 3) << 4);
          kF[base + lh*8 + (d & 7)] = hi;
          kF[base + (lh + 32)*8 + (d & 7)] = lo;
        } else {                  // vm -> branch 1 V-frags
          int c = po - 112;
          int ks = n >> 5, g = (n >> 3) & 3, j = n & 7, nt = c >> 4;
          int idx = ((((b*2 + 1)*32 + ks)*4 + nt)*64 + ((c & 15) | (g << 4)))*8 + j;
          vFh[idx] = hi; vFl[idx] = lo;
        }
      }
    }
  }
}

// ---------- K2: dual attention via MFMA + combine + gating ----------
#define RED_OFF 0        // [16 waves][16 nl][66]  = 16896
#define PS_OFF  16896    // [16 waves][16][36]     = 9216
#define SMX_OFF 26112    // [2][8][16]             = 256
#define SSM_OFF 26368    // [2][8][16]             = 256
#define INV_OFF 26624    // [2][16]                = 32
#define ZHM_OFF 26656    // [128][16]              = 2048
#define S_TOT   28704

__global__ __launch_bounds__(1024, 4) void k2_attn(
    int t,
    const float* __restrict__ q_buf,
    const unsigned short* __restrict__ kF,
    const unsigned short* __restrict__ vFh, const unsigned short* __restrict__ vFl,
    float* __restrict__ h_nxt, float* __restrict__ c_st,
    const float* __restrict__ z_wT, const float* __restrict__ z_b,
    const float* __restrict__ m_wT, const float* __restrict__ m_b,
    float* __restrict__ out)
{
  __shared__ __align__(16) float S[S_TOT];
  float* red  = S + RED_OFF;
  float* smMax= S + SMX_OFF;
  float* smSum= S + SSM_OFF;
  float* invL = S + INV_OFF;
  float* zhm  = S + ZHM_OFF;
  float* cbIn = S;              // alias red (after barrier)
  float* cbOut= S + 3072;       // alias red

  const int tid = threadIdx.x;
  const int bid = blockIdx.x;
  const int xcd = bid & 7;
  const int b = xcd >> 1;
  const int tile = ((bid >> 3) << 1) | (xcd & 1);   // 0..63
  const int n0 = tile * 16;

  const int wid  = tid >> 6;
  const int lane = tid & 63;
  const int brh  = wid >> 3;      // branch
  const int w    = wid & 7;       // wave within branch (owns m in [w*128,(w+1)*128))
  const int g    = lane >> 4;
  const int c16  = lane & 15;

  // ---- Q A-frags: A1 = [Qh|Qh], A2 = [Ql|0] ----
  s8v qh1, ql2;
  {
    const int dbase = (g & 1) * 8;
    #pragma unroll
    for (int j = 0; j < 8; j++) {
      float qv = q_buf[(b*16 + dbase + j)*NN + n0 + c16];
      unsigned short hi = bf16r(qv);
      unsigned short lo = bf16r(qv - bf16f(hi));
      qh1[j] = (short)hi;
      ql2[j] = (g < 2) ? (short)lo : (short)0;
    }
  }

  // ---- scores: 8 m-tiles per wave, 2 MFMA each (B = [Kh|Kl]) ----
  f4v acc[8];
  {
    const unsigned short* kp = kF + (((b*2 + brh)*64 + w*8)*64 + lane)*8;
    #pragma unroll
    for (int i = 0; i < 8; i++) {
      s8v bf = *(const s8v*)(kp + i*512);
      f4v z4 = {0.f, 0.f, 0.f, 0.f};
      z4 = __builtin_amdgcn_mfma_f32_16x16x32_bf16(ql2, bf, z4, 0, 0, 0);
      acc[i] = __builtin_amdgcn_mfma_f32_16x16x32_bf16(qh1, bf, z4, 0, 0, 0);
    }
  }

  // ---- softmax (rows nl = g*4+r, this wave holds 128 m per row) ----
  float Mrow[4];
  #pragma unroll
  for (int r = 0; r < 4; r++) {
    float m = acc[0][r];
    #pragma unroll
    for (int i = 1; i < 8; i++) m = fmaxf(m, acc[i][r]);
    m = fmaxf(m, __shfl_xor(m, 1));
    m = fmaxf(m, __shfl_xor(m, 2));
    m = fmaxf(m, __shfl_xor(m, 4));
    m = fmaxf(m, __shfl_xor(m, 8));
    if (c16 == 0) smMax[(brh*8 + w)*16 + g*4 + r] = m;
  }
  __syncthreads();
  #pragma unroll
  for (int r = 0; r < 4; r++) {
    float m = smMax[(brh*8 + 0)*16 + g*4 + r];
    #pragma unroll
    for (int w2 = 1; w2 < 8; w2++) m = fmaxf(m, smMax[(brh*8 + w2)*16 + g*4 + r]);
    Mrow[r] = m;
  }
  float rsum[4] = {0.f, 0.f, 0.f, 0.f};
  #pragma unroll
  for (int i = 0; i < 8; i++) {
    #pragma unroll
    for (int r = 0; r < 4; r++) {
      float p = __expf(acc[i][r] - Mrow[r]);
      acc[i][r] = p;
      rsum[r] += p;
    }
  }
  #pragma unroll
  for (int r = 0; r < 4; r++) {
    float s = rsum[r];
    s += __shfl_xor(s, 1); s += __shfl_xor(s, 2);
    s += __shfl_xor(s, 4); s += __shfl_xor(s, 8);
    if (c16 == 0) smSum[(brh*8 + w)*16 + g*4 + r] = s;
  }
  __syncthreads();
  if (w == 0 && c16 == 0) {
    #pragma unroll
    for (int r = 0; r < 4; r++) {
      float s = 0.f;
      #pragma unroll
      for (int w2 = 0; w2 < 8; w2++) s += smSum[(brh*8 + w2)*16 + g*4 + r];
      invL[brh*16 + g*4 + r] = 1.0f / s;
    }
  }

  // ---- PV: per wave, 4 k-steps of 32 m; wave-local P transpose; 3-term split ----
  f4v z0 = {0.f,0.f,0.f,0.f}, z1 = z0, z2 = z0, z3 = z0;
  float* myPS = S + PS_OFF + wid*576;   // [16][36]
  #pragma unroll
  for (int ks4 = 0; ks4 < 4; ks4++) {
    #pragma unroll
    for (int i2 = 0; i2 < 2; i2++) {
      #pragma unroll
      for (int r = 0; r < 4; r++)
        myPS[(g*4 + r)*36 + i2*16 + c16] = acc[ks4*2 + i2][r];
    }
    float4 pa = *(const float4*)&myPS[c16*36 + g*8];
    float4 pb = *(const float4*)&myPS[c16*36 + g*8 + 4];
    s8v ph, pl;
    {
      unsigned short h0 = bf16r(pa.x); ph[0] = (short)h0; pl[0] = (short)bf16r(pa.x - bf16f(h0));
      unsigned short h1 = bf16r(pa.y); ph[1] = (short)h1; pl[1] = (short)bf16r(pa.y - bf16f(h1));
      unsigned short h2 = bf16r(pa.z); ph[2] = (short)h2; pl[2] = (short)bf16r(pa.z - bf16f(h2));
      unsigned short h3 = bf16r(pa.w); ph[3] = (short)h3; pl[3] = (short)bf16r(pa.w - bf16f(h3));
      unsigned short h4 = bf16r(pb.x); ph[4] = (short)h4; pl[4] = (short)bf16r(pb.x - bf16f(h4));
      unsigned short h5 = bf16r(pb.y); ph[5] = (short)h5; pl[5] = (short)bf16r(pb.y - bf16f(h5));
      unsigned short h6 = bf16r(pb.z); ph[6] = (short)h6; pl[6] = (short)bf16r(pb.z - bf16f(h6));
      unsigned short h7 = bf16r(pb.w); ph[7] = (short)h7; pl[7] = (short)bf16r(pb.w - bf16f(h7));
    }
    const int ks = w*4 + ks4;
    const unsigned short* vph = vFh + ((((b*2 + brh)*32 + ks)*4)*64 + lane)*8;
    const unsigned short* vpl = vFl + ((((b*2 + brh)*32 + ks)*4)*64 + lane)*8;
    s8v vh0 = *(const s8v*)(vph);
    s8v vl0 = *(const s8v*)(vpl);
    z0 = __builtin_amdgcn_mfma_f32_16x16x32_bf16(ph, vh0, z0, 0,0,0);
    z0 = __builtin_amdgcn_mfma_f32_16x16x32_bf16(ph, vl0, z0, 0,0,0);
    z0 = __builtin_amdgcn_mfma_f32_16x16x32_bf16(pl, vh0, z0, 0,0,0);
    s8v vh1 = *(const s8v*)(vph + 512);
    s8v vl1 = *(const s8v*)(vpl + 512);
    z1 = __builtin_amdgcn_mfma_f32_16x16x32_bf16(ph, vh1, z1, 0,0,0);
    z1 = __builtin_amdgcn_mfma_f32_16x16x32_bf16(ph, vl1, z1, 0,0,0);
    z1 = __builtin_amdgcn_mfma_f32_16x16x32_bf16(pl, vh1, z1, 0,0,0);
    s8v vh2 = *(const s8v*)(vph + 1024);
    s8v vl2 = *(const s8v*)(vpl + 1024);
    z2 = __builtin_amdgcn_mfma_f32_16x16x32_bf16(ph, vh2, z2, 0,0,0);
    z2 = __builtin_amdgcn_mfma_f32_16x16x32_bf16(ph, vl2, z2, 0,0,0);
    z2 = __builtin_amdgcn_mfma_f32_16x16x32_bf16(pl, vh2, z2, 0,0,0);
    s8v vh3 = *(const s8v*)(vph + 1536);
    s8v vl3 = *(const s8v*)(vpl + 1536);
    z3 = __builtin_amdgcn_mfma_f32_16x16x32_bf16(ph, vh3, z3, 0,0,0);
    z3 = __builtin_amdgcn_mfma_f32_16x16x32_bf16(ph, vl3, z3, 0,0,0);
    z3 = __builtin_amdgcn_mfma_f32_16x16x32_bf16(pl, vh3, z3, 0,0,0);
  }

  // ---- write partials, reduce 8 waves, normalize -> zhm ----
  {
    float* rw = red + wid*1056;
    #pragma unroll
    for (int r = 0; r < 4; r++) {
      rw[(g*4 + r)*66 +  0 + c16] = z0[r];
      rw[(g*4 + r)*66 + 16 + c16] = z1[r];
      rw[(g*4 + r)*66 + 32 + c16] = z2[r];
      rw[(g*4 + r)*66 + 48 + c16] = z3[r];
    }
  }
  __syncthreads();
  {
    const int br2 = tid >> 9;
    const int sub = tid & 511;
    const int nlr = sub >> 5;
    const int cc0 = (sub & 31) * 2;
    float iv = invL[br2*16 + nlr];
    #pragma unroll
    for (int u = 0; u < 2; u++) {
      int cc = cc0 + u;
      float s = 0.f;
      #pragma unroll
      for (int w2 = 0; w2 < 8; w2++)
        s += red[(br2*8 + w2)*1056 + nlr*66 + cc];
      zhm[(br2*64 + cc)*16 + nlr] = s * iv;
    }
  }
  __syncthreads();

  // ---- zz = z_w @ [zh; zm] + z_b  (+ stage hf rows); cbIn aliases red ----
  {
    const int oc  = tid & 127;
    const int nl0 = (tid >> 7) * 2;
    float s0 = z_b[oc], s1 = s0;
    for (int k = 0; k < 128; k++) {
      float ww = z_wT[k*128 + oc];
      float2 zz2 = *(const float2*)&zhm[k*16 + nl0];
      s0 = fmaf(ww, zz2.x, s0); s1 = fmaf(ww, zz2.y, s1);
    }
    cbIn[oc*16 + nl0]     = s0;
    cbIn[oc*16 + nl0 + 1] = s1;
    const int c = tid >> 4, nn = tid & 15;
    cbIn[(128 + c)*16 + nn] = h_nxt[(b*64 + c)*NN + n0 + nn];
  }
  __syncthreads();

  // ---- comb = m_w @ [zz; hf] + m_b ----
  if (tid < 768) {
    const int oc = tid >> 2;
    const int nl0 = (tid & 3) * 4;
    float4 a; a.x = a.y = a.z = a.w = m_b[oc];
    for (int k = 0; k < 192; k++) {
      float ww = m_wT[k*192 + oc];
      float4 v = *(const float4*)&cbIn[k*16 + nl0];
      a.x = fmaf(ww, v.x, a.x); a.y = fmaf(ww, v.y, a.y);
      a.z = fmaf(ww, v.z, a.z); a.w = fmaf(ww, v.w, a.w);
    }
    *(float4*)&cbOut[oc*16 + nl0] = a;
  }
  __syncthreads();

  // ---- gating ----
  {
    const int c = tid >> 4, nn = tid & 15;
    const int n = n0 + nn;
    float mo = cbOut[c*16 + nn];
    float mg = cbOut[(64 + c)*16 + nn];
    float mi = cbOut[(128 + c)*16 + nn];
    float mf = c_st[(b*64 + c)*NN + n];
    float mis = sigm(mi);
    float nmf = (1.0f - mis)*mf + mis*tanh_f(mg);
    float nhf = sigm(mo)*nmf;
    c_st[(b*64 + c)*NN + n] = nmf;
    h_nxt[(b*64 + c)*NN + n] = nhf;
    out[((b*64 + c)*SS + t)*NN + n] = nhf;
  }
}

extern "C" void kernel_launch(void* const* d_in, const int* in_sizes, int n_in,
                              void* d_out, int out_size, void* d_ws, size_t ws_size,
                              hipStream_t stream) {
  const float* X      = (const float*)d_in[0];
  const float* conv_w = (const float*)d_in[1];
  const float* conv_b = (const float*)d_in[2];
  const float* W_ci   = (const float*)d_in[3];
  const float* W_cf   = (const float*)d_in[4];
  const float* W_co   = (const float*)d_in[5];
  const float* qw  = (const float*)d_in[6];
  const float* qb  = (const float*)d_in[7];
  const float* kw  = (const float*)d_in[8];
  const float* kb  = (const float*)d_in[9];
  const float* k2w = (const float*)d_in[10];
  const float* k2b = (const float*)d_in[11];
  const float* vw  = (const float*)d_in[12];
  const float* vb  = (const float*)d_in[13];
  const float* v2w = (const float*)d_in[14];
  const float* v2b = (const float*)d_in[15];
  const float* z_w = (const float*)d_in[16];
  const float* z_b = (const float*)d_in[17];
  const float* m_w = (const float*)d_in[18];
  const float* m_b = (const float*)d_in[19];
  float* out = (float*)d_out;

  float* ws = (float*)d_ws;
  unsigned short* Whi = (unsigned short*)ws;  ws += 147456;   // 294912 ushorts
  unsigned short* Wlo = (unsigned short*)ws;  ws += 147456;
  float* z_wT   = ws;             ws += 128*128;
  float* m_wT   = ws;             ws += 192*192;
  float* h_A    = ws;             ws += NB*64*NN;
  float* h_B    = ws;             ws += NB*64*NN;
  float* c_st   = ws;             ws += NB*64*NN;
  float* q_buf  = ws;             ws += NB*16*NN;
  unsigned short* kF  = (unsigned short*)ws;  ws += 131072;   // 4b*2br*64mt*64*8 ushorts
  unsigned short* vFh = (unsigned short*)ws;  ws += 131072;   // 4b*2br*32ks*4nt*64*8
  unsigned short* vFl = (unsigned short*)ws;  ws += 131072;

  hipLaunchKernelGGL(k0_prep, dim3(256), dim3(256), 0, stream,
                     conv_w, z_w, m_w, Whi, Wlo, z_wT, m_wT, h_A, c_st);
  for (int t = 0; t < 16; t++) {
    const float* h_cur = (t & 1) ? h_B : h_A;
    float* h_nxt       = (t & 1) ? h_A : h_B;
    hipLaunchKernelGGL(k1_conv_lstm_proj, dim3(256), dim3(512), 0, stream,
        t, X, Whi, Wlo, conv_b, W_ci, W_cf, W_co,
        qw, qb, kw, kb, k2w, k2b, vw, vb, v2w, v2b,
        h_cur, h_nxt, c_st, q_buf, kF, vFh, vFl);
    hipLaunchKernelGGL(k2_attn, dim3(256), dim3(1024), 0, stream,
        t, q_buf, kF, vFh, vFl, h_nxt, c_st,
        z_wT, z_b, m_wT, m_b, out);
  }
}

// Round 5
// 875.914 us; speedup vs baseline: 3.1343x; 1.0303x over previous
//
#include <hip/hip_runtime.h>
#include <math.h>

#define NB 4
#define SS 16
#define NN 1024        // H*W

typedef short s8v __attribute__((ext_vector_type(8)));    // 8 bf16 (4 VGPR)
typedef float f4v __attribute__((ext_vector_type(4)));    // MFMA accumulator

__device__ __forceinline__ float sigm(float x) {
  return 1.0f / (1.0f + __expf(-x));
}
__device__ __forceinline__ float tanh_f(float x) {
  float e = __expf(2.0f * x);
  return 1.0f - 2.0f / (1.0f + e);
}
__device__ __forceinline__ unsigned short bf16r(float x) {   // RNE float->bf16
  unsigned int u = __float_as_uint(x);
  u = (u + 0x7FFFu + ((u >> 16) & 1u)) >> 16;
  return (unsigned short)u;
}
__device__ __forceinline__ float bf16f(unsigned short h) {
  return __uint_as_float(((unsigned int)h) << 16);
}

// ---------- prep: conv-weight split/pack + transposes + zero states ----------
__global__ void k0_prep(const float* __restrict__ conv_w, const float* __restrict__ z_w,
                        const float* __restrict__ m_w,
                        unsigned short* __restrict__ Whi, unsigned short* __restrict__ Wlo,
                        float* __restrict__ z_wT, float* __restrict__ m_wT,
                        float* __restrict__ h_A, float* __restrict__ c_st) {
  int stride = gridDim.x * blockDim.x;
  int i0 = blockIdx.x * blockDim.x + threadIdx.x;
  for (int i = i0; i < 256*1152; i += stride) {
    int oc = i / 1152, k = i - oc*1152;          // k = ic*9 + ky*3 + kx
    float v = conv_w[i];
    unsigned short hi = bf16r(v);
    unsigned short lo = bf16r(v - bf16f(hi));
    int mt = oc >> 4, i16 = oc & 15;
    int ks = k >> 5, kk = k & 31;
    int lane = i16 | ((kk >> 3) << 4);
    int pos = ((mt*36 + ks)*64 + lane)*8 + (kk & 7);
    Whi[pos] = hi;
    Wlo[pos] = lo;
  }
  for (int i = i0; i < 128*128; i += stride) {
    int oc = i >> 7, k = i & 127;
    z_wT[k*128 + oc] = z_w[i];
  }
  for (int i = i0; i < 192*192; i += stride) {
    int oc = i / 192, k = i - oc*192;
    m_wT[k*192 + oc] = m_w[i];
  }
  for (int i = i0; i < NB*64*NN; i += stride) { h_A[i] = 0.0f; c_st[i] = 0.0f; }
}

// ---------- K1: conv (MFMA split-bf16) + LSTM + projections (512 threads) ----------
__global__ __launch_bounds__(512) void k1_conv_lstm_proj(
    int t,
    const float* __restrict__ X,
    const unsigned short* __restrict__ Whi, const unsigned short* __restrict__ Wlo,
    const float* __restrict__ conv_b,
    const float* __restrict__ W_ci, const float* __restrict__ W_cf, const float* __restrict__ W_co,
    const float* __restrict__ qw, const float* __restrict__ qb,
    const float* __restrict__ kw, const float* __restrict__ kb,
    const float* __restrict__ k2w, const float* __restrict__ k2b,
    const float* __restrict__ vw, const float* __restrict__ vb,
    const float* __restrict__ v2w, const float* __restrict__ v2b,
    const float* __restrict__ h_cur, float* __restrict__ h_nxt,
    float* __restrict__ c_st,
    float* __restrict__ q_buf,
    unsigned short* __restrict__ kF,
    unsigned short* __restrict__ vFh, unsigned short* __restrict__ vFl)
{
  __shared__ __align__(16) unsigned short Ihi_l[36*64*8];      // im2col in B-frag order
  __shared__ __align__(16) unsigned short Ilo_l[36*64*8];
  __shared__ __align__(16) float gates_l[256*17];              // [oc][x]; later proj_l[176][16]
  __shared__ __align__(16) float h_l[16*68];                   // [x][c]
  __shared__ __align__(16) float c_l[16*68];

  const int tid = threadIdx.x;
  const int bid = blockIdx.x;
  const int b  = bid >> 6;
  const int y  = (bid >> 1) & 31;
  const int x0 = (bid & 1) * 16;
  const int mt = bid & 63;          // this block's 16-col m-tile (= n>>4)
  const int n0 = y*32 + x0;

  // ---- phase 0 (fused): global load -> bf16 hi/lo -> im2col B-frags in LDS ----
  for (int idx = tid; idx < 128*3*18; idx += 512) {
    int col = idx % 18;
    int rest = idx / 18;
    int dy = rest % 3;
    int ic = rest / 3;
    int gy = y + dy - 1;
    int gx = x0 + col - 1;
    float v = 0.0f;
    if ((unsigned)gy < 32u && (unsigned)gx < 32u) {
      if (ic < 64) v = X[(((b*64 + ic)*SS + t)*NN) + gy*32 + gx];
      else         v = h_cur[((b*64 + (ic-64))*NN) + gy*32 + gx];
    }
    unsigned short hi = bf16r(v);
    unsigned short lo = bf16r(v - bf16f(hi));
    int kbase = ic*9 + dy*3;
    #pragma unroll
    for (int dx = 0; dx < 3; dx++) {
      int n = col - dx;
      if ((unsigned)n < 16u) {
        int k = kbase + dx;
        int ks = k >> 5, kk = k & 31;
        int pos = (ks*64 + (n | ((kk >> 3) << 4)))*8 + (kk & 7);
        Ihi_l[pos] = hi;
        Ilo_l[pos] = lo;
      }
    }
  }
  __syncthreads();

  // ---- phase 2: MFMA K-loop (8 waves x 2 m-tiles; 3-term split-bf16) ----
  {
    const int lane = tid & 63;
    const int wid  = tid >> 6;          // 0..7
    const int mt0 = wid*2, mt1 = mt0 + 1;
    f4v acc0 = {0.f, 0.f, 0.f, 0.f};
    f4v acc1 = {0.f, 0.f, 0.f, 0.f};
    const s8v* Ah0 = (const s8v*)Whi + (mt0*36)*64 + lane;
    const s8v* Al0 = (const s8v*)Wlo + (mt0*36)*64 + lane;
    const s8v* Ah1 = (const s8v*)Whi + (mt1*36)*64 + lane;
    const s8v* Al1 = (const s8v*)Wlo + (mt1*36)*64 + lane;
    const s8v* Bh  = (const s8v*)Ihi_l + lane;
    const s8v* Bl  = (const s8v*)Ilo_l + lane;
    #pragma unroll 2
    for (int ks = 0; ks < 36; ks++) {
      s8v a0h = Ah0[ks*64];
      s8v a0l = Al0[ks*64];
      s8v a1h = Ah1[ks*64];
      s8v a1l = Al1[ks*64];
      s8v bh  = Bh[ks*64];
      s8v bl  = Bl[ks*64];
      acc0 = __builtin_amdgcn_mfma_f32_16x16x32_bf16(a0h, bh, acc0, 0, 0, 0);
      acc1 = __builtin_amdgcn_mfma_f32_16x16x32_bf16(a1h, bh, acc1, 0, 0, 0);
      acc0 = __builtin_amdgcn_mfma_f32_16x16x32_bf16(a0l, bh, acc0, 0, 0, 0);
      acc1 = __builtin_amdgcn_mfma_f32_16x16x32_bf16(a1l, bh, acc1, 0, 0, 0);
      acc0 = __builtin_amdgcn_mfma_f32_16x16x32_bf16(a0h, bl, acc0, 0, 0, 0);
      acc1 = __builtin_amdgcn_mfma_f32_16x16x32_bf16(a1h, bl, acc1, 0, 0, 0);
    }
    const int colx = lane & 15;
    const int rb   = (lane >> 4) * 4;
    #pragma unroll
    for (int r = 0; r < 4; r++) {
      gates_l[(mt0*16 + rb + r)*17 + colx] = acc0[r];
      gates_l[(mt1*16 + rb + r)*17 + colx] = acc1[r];
    }
  }
  __syncthreads();

  // ---- phase 3: LSTM elementwise (2 channels per thread) ----
  {
    const int x  = tid & 15;
    const int c2 = tid >> 4;      // 0..31
    const int n  = n0 + x;
    #pragma unroll
    for (int j = 0; j < 2; j++) {
      int c = c2 + j*32;
      float ig = gates_l[(c      )*17 + x] + conv_b[c];
      float fg = gates_l[( 64 + c)*17 + x] + conv_b[ 64 + c];
      float gg = gates_l[(128 + c)*17 + x] + conv_b[128 + c];
      float og = gates_l[(192 + c)*17 + x] + conv_b[192 + c];
      float cp = c_st[(b*64 + c)*NN + n];
      float i_ = sigm(ig + W_ci[c*NN + n] * cp);
      float f_ = sigm(fg + W_cf[c*NN + n] * cp);
      float cn = f_*cp + i_*tanh_f(gg);
      float o_ = sigm(og + W_co[c*NN + n] * cn);
      float hn = o_*tanh_f(cn);
      h_nxt[(b*64 + c)*NN + n] = hn;
      c_st[(b*64 + c)*NN + n] = cn;
      h_l[x*68 + c] = hn;
      c_l[x*68 + c] = cn;
    }
  }
  __syncthreads();

  // ---- phase 4a: projections -> LDS staging (proj_l aliases gates_l) ----
  float* proj_l = gates_l;        // gates fully consumed in phase 3
  for (int r0 = 0; r0 < 6; r0++) {
    int task = tid + r0*512;
    if (task < 176*16) {
      int po = task >> 4, x = task & 15;
      const float* src = (po < 96) ? &h_l[x*68] : &c_l[x*68];
      const float* w; float bias;
      if (po < 16)       { w = qw  + po*64;        bias = qb[po]; }
      else if (po < 32)  { w = kw  + (po-16)*64;   bias = kb[po-16]; }
      else if (po < 96)  { w = vw  + (po-32)*64;   bias = vb[po-32]; }
      else if (po < 112) { w = k2w + (po-96)*64;   bias = k2b[po-96]; }
      else               { w = v2w + (po-112)*64;  bias = v2b[po-112]; }
      float s = bias;
      #pragma unroll
      for (int k = 0; k < 64; k += 4) {
        float4 wv = *(const float4*)&w[k];
        float4 sv = *(const float4*)&src[k];
        s = fmaf(wv.x, sv.x, s); s = fmaf(wv.y, sv.y, s);
        s = fmaf(wv.z, sv.z, s); s = fmaf(wv.w, sv.w, s);
      }
      proj_l[po*16 + x] = s;
    }
  }
  __syncthreads();

  // ---- phase 4b: coalesced fragment emission ----
  // q: 256 float stores (16-float runs per row)
  if (tid < 256) {
    int d = tid >> 4, x = tid & 15;
    q_buf[(b*16 + d)*NN + n0 + x] = proj_l[d*16 + x];
  }
  // K frags: 512 uint tasks; kF block for (branch, mt) is 512 contiguous ushorts
  {
    int brh2 = tid >> 8;            // branch
    int lh   = (tid >> 2) & 63;     // fragment "lane-half" row
    int j2   = tid & 3;             // packs d&7 = 2*j2, 2*j2+1
    int p    = lh >> 4;             // 0,1: hi planes; 2,3: lo planes
    int x    = lh & 15;
    int d0   = ((p & 1) << 3) | (j2 << 1);
    int Koff = brh2 ? 96 : 16;
    float v0 = proj_l[(Koff + d0)*16 + x];
    float v1 = proj_l[(Koff + d0 + 1)*16 + x];
    unsigned short h0 = bf16r(v0), h1 = bf16r(v1);
    unsigned short u0, u1;
    if (p < 2) { u0 = h0; u1 = h1; }
    else       { u0 = bf16r(v0 - bf16f(h0)); u1 = bf16r(v1 - bf16f(h1)); }
    unsigned int* dst = (unsigned int*)(kF + ((b*2 + brh2)*64 + mt)*512);
    dst[lh*4 + j2] = (unsigned)u0 | ((unsigned)u1 << 16);
  }
  // V frags: 2048 uint tasks (4 iters); 256-ushort contiguous runs per (plane,branch,nt)
  {
    const int ks = y;
    const int g0 = x0 >> 3;         // 0 or 2
    #pragma unroll
    for (int it = 0; it < 4; it++) {
      int ct    = tid + it*512;
      int plane = ct >> 10;         // 0 = vFh, 1 = vFl
      int brh2  = (ct >> 9) & 1;
      int nt    = (ct >> 7) & 3;
      int li    = (ct >> 2) & 31;
      int j2    = ct & 3;
      int lane2 = g0*16 + li;
      int cch   = nt*16 + (lane2 & 15);
      int xx    = ((li >> 4) << 3) | (j2 << 1);
      int Voff  = brh2 ? 112 : 32;
      float v0 = proj_l[(Voff + cch)*16 + xx];
      float v1 = proj_l[(Voff + cch)*16 + xx + 1];
      unsigned short h0 = bf16r(v0), h1 = bf16r(v1);
      unsigned short u0, u1;
      if (plane == 0) { u0 = h0; u1 = h1; }
      else            { u0 = bf16r(v0 - bf16f(h0)); u1 = bf16r(v1 - bf16f(h1)); }
      unsigned short* basep = (plane ? vFl : vFh) + (((b*2 + brh2)*32 + ks)*4 + nt)*512;
      ((unsigned int*)basep)[lane2*4 + j2] = (unsigned)u0 | ((unsigned)u1 << 16);
    }
  }
}

// ---------- K2: dual attention via MFMA + combine + gating ----------
#define RED_OFF 0        // [16 waves][16 nl][66]  = 16896
#define PS_OFF  16896    // [16 waves][16][36]     = 9216
#define SMX_OFF 26112    // [2][8][16]             = 256
#define SSM_OFF 26368    // [2][8][16]             = 256
#define INV_OFF 26624    // [2][16]                = 32
#define ZHM_OFF 26656    // [128][16]              = 2048
#define S_TOT   28704

__global__ __launch_bounds__(1024, 4) void k2_attn(
    int t,
    const float* __restrict__ q_buf,
    const unsigned short* __restrict__ kF,
    const unsigned short* __restrict__ vFh, const unsigned short* __restrict__ vFl,
    float* __restrict__ h_nxt, float* __restrict__ c_st,
    const float* __restrict__ z_wT, const float* __restrict__ z_b,
    const float* __restrict__ m_wT, const float* __restrict__ m_b,
    float* __restrict__ out)
{
  __shared__ __align__(16) float S[S_TOT];
  float* red  = S + RED_OFF;
  float* smMax= S + SMX_OFF;
  float* smSum= S + SSM_OFF;
  float* invL = S + INV_OFF;
  float* zhm  = S + ZHM_OFF;
  float* cbIn = S;              // alias red (after barrier)
  float* cbOut= S + 3072;       // alias red

  const int tid = threadIdx.x;
  const int bid = blockIdx.x;
  const int xcd = bid & 7;
  const int b = xcd >> 1;
  const int tile = ((bid >> 3) << 1) | (xcd & 1);   // 0..63
  const int n0 = tile * 16;

  const int wid  = tid >> 6;
  const int lane = tid & 63;
  const int brh  = wid >> 3;      // branch
  const int w    = wid & 7;       // wave within branch (owns m in [w*128,(w+1)*128))
  const int g    = lane >> 4;
  const int c16  = lane & 15;

  // ---- Q A-frags: A1 = [Qh|Qh], A2 = [Ql|0] ----
  s8v qh1, ql2;
  {
    const int dbase = (g & 1) * 8;
    #pragma unroll
    for (int j = 0; j < 8; j++) {
      float qv = q_buf[(b*16 + dbase + j)*NN + n0 + c16];
      unsigned short hi = bf16r(qv);
      unsigned short lo = bf16r(qv - bf16f(hi));
      qh1[j] = (short)hi;
      ql2[j] = (g < 2) ? (short)lo : (short)0;
    }
  }

  // ---- scores: 8 m-tiles per wave, 2 MFMA each (B = [Kh|Kl]) ----
  f4v acc[8];
  {
    const unsigned short* kp = kF + (((b*2 + brh)*64 + w*8)*64 + lane)*8;
    #pragma unroll
    for (int i = 0; i < 8; i++) {
      s8v bf = *(const s8v*)(kp + i*512);
      f4v z4 = {0.f, 0.f, 0.f, 0.f};
      z4 = __builtin_amdgcn_mfma_f32_16x16x32_bf16(ql2, bf, z4, 0, 0, 0);
      acc[i] = __builtin_amdgcn_mfma_f32_16x16x32_bf16(qh1, bf, z4, 0, 0, 0);
    }
  }

  // ---- softmax (rows nl = g*4+r, this wave holds 128 m per row) ----
  float Mrow[4];
  #pragma unroll
  for (int r = 0; r < 4; r++) {
    float m = acc[0][r];
    #pragma unroll
    for (int i = 1; i < 8; i++) m = fmaxf(m, acc[i][r]);
    m = fmaxf(m, __shfl_xor(m, 1));
    m = fmaxf(m, __shfl_xor(m, 2));
    m = fmaxf(m, __shfl_xor(m, 4));
    m = fmaxf(m, __shfl_xor(m, 8));
    if (c16 == 0) smMax[(brh*8 + w)*16 + g*4 + r] = m;
  }
  __syncthreads();
  #pragma unroll
  for (int r = 0; r < 4; r++) {
    float m = smMax[(brh*8 + 0)*16 + g*4 + r];
    #pragma unroll
    for (int w2 = 1; w2 < 8; w2++) m = fmaxf(m, smMax[(brh*8 + w2)*16 + g*4 + r]);
    Mrow[r] = m;
  }
  float rsum[4] = {0.f, 0.f, 0.f, 0.f};
  #pragma unroll
  for (int i = 0; i < 8; i++) {
    #pragma unroll
    for (int r = 0; r < 4; r++) {
      float p = __expf(acc[i][r] - Mrow[r]);
      acc[i][r] = p;
      rsum[r] += p;
    }
  }
  #pragma unroll
  for (int r = 0; r < 4; r++) {
    float s = rsum[r];
    s += __shfl_xor(s, 1); s += __shfl_xor(s, 2);
    s += __shfl_xor(s, 4); s += __shfl_xor(s, 8);
    if (c16 == 0) smSum[(brh*8 + w)*16 + g*4 + r] = s;
  }
  __syncthreads();
  if (w == 0 && c16 == 0) {
    #pragma unroll
    for (int r = 0; r < 4; r++) {
      float s = 0.f;
      #pragma unroll
      for (int w2 = 0; w2 < 8; w2++) s += smSum[(brh*8 + w2)*16 + g*4 + r];
      invL[brh*16 + g*4 + r] = 1.0f / s;
    }
  }

  // ---- PV: per wave, 4 k-steps of 32 m; wave-local P transpose; 3-term split ----
  f4v z0 = {0.f,0.f,0.f,0.f}, z1 = z0, z2 = z0, z3 = z0;
  float* myPS = S + PS_OFF + wid*576;   // [16][36]
  #pragma unroll
  for (int ks4 = 0; ks4 < 4; ks4++) {
    #pragma unroll
    for (int i2 = 0; i2 < 2; i2++) {
      #pragma unroll
      for (int r = 0; r < 4; r++)
        myPS[(g*4 + r)*36 + i2*16 + c16] = acc[ks4*2 + i2][r];
    }
    float4 pa = *(const float4*)&myPS[c16*36 + g*8];
    float4 pb = *(const float4*)&myPS[c16*36 + g*8 + 4];
    s8v ph, pl;
    {
      unsigned short h0 = bf16r(pa.x); ph[0] = (short)h0; pl[0] = (short)bf16r(pa.x - bf16f(h0));
      unsigned short h1 = bf16r(pa.y); ph[1] = (short)h1; pl[1] = (short)bf16r(pa.y - bf16f(h1));
      unsigned short h2 = bf16r(pa.z); ph[2] = (short)h2; pl[2] = (short)bf16r(pa.z - bf16f(h2));
      unsigned short h3 = bf16r(pa.w); ph[3] = (short)h3; pl[3] = (short)bf16r(pa.w - bf16f(h3));
      unsigned short h4 = bf16r(pb.x); ph[4] = (short)h4; pl[4] = (short)bf16r(pb.x - bf16f(h4));
      unsigned short h5 = bf16r(pb.y); ph[5] = (short)h5; pl[5] = (short)bf16r(pb.y - bf16f(h5));
      unsigned short h6 = bf16r(pb.z); ph[6] = (short)h6; pl[6] = (short)bf16r(pb.z - bf16f(h6));
      unsigned short h7 = bf16r(pb.w); ph[7] = (short)h7; pl[7] = (short)bf16r(pb.w - bf16f(h7));
    }
    const int ks = w*4 + ks4;
    const unsigned short* vph = vFh + ((((b*2 + brh)*32 + ks)*4)*64 + lane)*8;
    const unsigned short* vpl = vFl + ((((b*2 + brh)*32 + ks)*4)*64 + lane)*8;
    s8v vh0 = *(const s8v*)(vph);
    s8v vl0 = *(const s8v*)(vpl);
    z0 = __builtin_amdgcn_mfma_f32_16x16x32_bf16(ph, vh0, z0, 0,0,0);
    z0 = __builtin_amdgcn_mfma_f32_16x16x32_bf16(ph, vl0, z0, 0,0,0);
    z0 = __builtin_amdgcn_mfma_f32_16x16x32_bf16(pl, vh0, z0, 0,0,0);
    s8v vh1 = *(const s8v*)(vph + 512);
    s8v vl1 = *(const s8v*)(vpl + 512);
    z1 = __builtin_amdgcn_mfma_f32_16x16x32_bf16(ph, vh1, z1, 0,0,0);
    z1 = __builtin_amdgcn_mfma_f32_16x16x32_bf16(ph, vl1, z1, 0,0,0);
    z1 = __builtin_amdgcn_mfma_f32_16x16x32_bf16(pl, vh1, z1, 0,0,0);
    s8v vh2 = *(const s8v*)(vph + 1024);
    s8v vl2 = *(const s8v*)(vpl + 1024);
    z2 = __builtin_amdgcn_mfma_f32_16x16x32_bf16(ph, vh2, z2, 0,0,0);
    z2 = __builtin_amdgcn_mfma_f32_16x16x32_bf16(ph, vl2, z2, 0,0,0);
    z2 = __builtin_amdgcn_mfma_f32_16x16x32_bf16(pl, vh2, z2, 0,0,0);
    s8v vh3 = *(const s8v*)(vph + 1536);
    s8v vl3 = *(const s8v*)(vpl + 1536);
    z3 = __builtin_amdgcn_mfma_f32_16x16x32_bf16(ph, vh3, z3, 0,0,0);
    z3 = __builtin_amdgcn_mfma_f32_16x16x32_bf16(ph, vl3, z3, 0,0,0);
    z3 = __builtin_amdgcn_mfma_f32_16x16x32_bf16(pl, vh3, z3, 0,0,0);
  }

  // ---- write partials, reduce 8 waves, normalize -> zhm ----
  {
    float* rw = red + wid*1056;
    #pragma unroll
    for (int r = 0; r < 4; r++) {
      rw[(g*4 + r)*66 +  0 + c16] = z0[r];
      rw[(g*4 + r)*66 + 16 + c16] = z1[r];
      rw[(g*4 + r)*66 + 32 + c16] = z2[r];
      rw[(g*4 + r)*66 + 48 + c16] = z3[r];
    }
  }
  __syncthreads();
  {
    const int br2 = tid >> 9;
    const int sub = tid & 511;
    const int nlr = sub >> 5;
    const int cc0 = (sub & 31) * 2;
    float iv = invL[br2*16 + nlr];
    #pragma unroll
    for (int u = 0; u < 2; u++) {
      int cc = cc0 + u;
      float s = 0.f;
      #pragma unroll
      for (int w2 = 0; w2 < 8; w2++)
        s += red[(br2*8 + w2)*1056 + nlr*66 + cc];
      zhm[(br2*64 + cc)*16 + nlr] = s * iv;
    }
  }
  __syncthreads();

  // ---- zz = z_w @ [zh; zm] + z_b  (+ stage hf rows); cbIn aliases red ----
  {
    const int oc  = tid & 127;
    const int nl0 = (tid >> 7) * 2;
    float s0 = z_b[oc], s1 = s0;
    for (int k = 0; k < 128; k++) {
      float ww = z_wT[k*128 + oc];
      float2 zz2 = *(const float2*)&zhm[k*16 + nl0];
      s0 = fmaf(ww, zz2.x, s0); s1 = fmaf(ww, zz2.y, s1);
    }
    cbIn[oc*16 + nl0]     = s0;
    cbIn[oc*16 + nl0 + 1] = s1;
    const int c = tid >> 4, nn = tid & 15;
    cbIn[(128 + c)*16 + nn] = h_nxt[(b*64 + c)*NN + n0 + nn];
  }
  __syncthreads();

  // ---- comb = m_w @ [zz; hf] + m_b ----
  if (tid < 768) {
    const int oc = tid >> 2;
    const int nl0 = (tid & 3) * 4;
    float4 a; a.x = a.y = a.z = a.w = m_b[oc];
    for (int k = 0; k < 192; k++) {
      float ww = m_wT[k*192 + oc];
      float4 v = *(const float4*)&cbIn[k*16 + nl0];
      a.x = fmaf(ww, v.x, a.x); a.y = fmaf(ww, v.y, a.y);
      a.z = fmaf(ww, v.z, a.z); a.w = fmaf(ww, v.w, a.w);
    }
    *(float4*)&cbOut[oc*16 + nl0] = a;
  }
  __syncthreads();

  // ---- gating ----
  {
    const int c = tid >> 4, nn = tid & 15;
    const int n = n0 + nn;
    float mo = cbOut[c*16 + nn];
    float mg = cbOut[(64 + c)*16 + nn];
    float mi = cbOut[(128 + c)*16 + nn];
    float mf = c_st[(b*64 + c)*NN + n];
    float mis = sigm(mi);
    float nmf = (1.0f - mis)*mf + mis*tanh_f(mg);
    float nhf = sigm(mo)*nmf;
    c_st[(b*64 + c)*NN + n] = nmf;
    h_nxt[(b*64 + c)*NN + n] = nhf;
    out[((b*64 + c)*SS + t)*NN + n] = nhf;
  }
}

extern "C" void kernel_launch(void* const* d_in, const int* in_sizes, int n_in,
                              void* d_out, int out_size, void* d_ws, size_t ws_size,
                              hipStream_t stream) {
  const float* X      = (const float*)d_in[0];
  const float* conv_w = (const float*)d_in[1];
  const float* conv_b = (const float*)d_in[2];
  const float* W_ci   = (const float*)d_in[3];
  const float* W_cf   = (const float*)d_in[4];
  const float* W_co   = (const float*)d_in[5];
  const float* qw  = (const float*)d_in[6];
  const float* qb  = (const float*)d_in[7];
  const float* kw  = (const float*)d_in[8];
  const float* kb  = (const float*)d_in[9];
  const float* k2w = (const float*)d_in[10];
  const float* k2b = (const float*)d_in[11];
  const float* vw  = (const float*)d_in[12];
  const float* vb  = (const float*)d_in[13];
  const float* v2w = (const float*)d_in[14];
  const float* v2b = (const float*)d_in[15];
  const float* z_w = (const float*)d_in[16];
  const float* z_b = (const float*)d_in[17];
  const float* m_w = (const float*)d_in[18];
  const float* m_b = (const float*)d_in[19];
  float* out = (float*)d_out;

  float* ws = (float*)d_ws;
  unsigned short* Whi = (unsigned short*)ws;  ws += 147456;   // 294912 ushorts
  unsigned short* Wlo = (unsigned short*)ws;  ws += 147456;
  float* z_wT   = ws;             ws += 128*128;
  float* m_wT   = ws;             ws += 192*192;
  float* h_A    = ws;             ws += NB*64*NN;
  float* h_B    = ws;             ws += NB*64*NN;
  float* c_st   = ws;             ws += NB*64*NN;
  float* q_buf  = ws;             ws += NB*16*NN;
  unsigned short* kF  = (unsigned short*)ws;  ws += 131072;   // 4b*2br*64mt*64*8 ushorts
  unsigned short* vFh = (unsigned short*)ws;  ws += 131072;   // 4b*2br*32ks*4nt*64*8
  unsigned short* vFl = (unsigned short*)ws;  ws += 131072;

  hipLaunchKernelGGL(k0_prep, dim3(256), dim3(256), 0, stream,
                     conv_w, z_w, m_w, Whi, Wlo, z_wT, m_wT, h_A, c_st);
  for (int t = 0; t < 16; t++) {
    const float* h_cur = (t & 1) ? h_B : h_A;
    float* h_nxt       = (t & 1) ? h_A : h_B;
    hipLaunchKernelGGL(k1_conv_lstm_proj, dim3(256), dim3(512), 0, stream,
        t, X, Whi, Wlo, conv_b, W_ci, W_cf, W_co,
        qw, qb, kw, kb, k2w, k2b, vw, vb, v2w, v2b,
        h_cur, h_nxt, c_st, q_buf, kF, vFh, vFl);
    hipLaunchKernelGGL(k2_attn, dim3(256), dim3(1024), 0, stream,
        t, q_buf, kF, vFh, vFl, h_nxt, c_st,
        z_wT, z_b, m_wT, m_b, out);
  }
}